// Round 8
// baseline (303.371 us; speedup 1.0000x reference)
//
#include <hip/hip_runtime.h>
#include <math.h>

#define NDIM 4096
#define NNSZ ((size_t)NDIM*(size_t)NDIM)

typedef __attribute__((ext_vector_type(8))) short short8;
typedef __attribute__((ext_vector_type(4))) float f32x4;

// float -> bf16 RNE
__device__ __forceinline__ unsigned short f2bf(float x) {
  unsigned u = __float_as_uint(x);
  u += 0x7FFFu + ((u >> 16) & 1u);
  return (unsigned short)(u >> 16);
}
__device__ __forceinline__ float bf2f(unsigned short u) {
  return __uint_as_float(((unsigned)u) << 16);
}

// ---------------------------------------------------------------------------
// interaction term: tanh(0.6*mult + 0.4*cond) from relations 0..2 at one elem
// ---------------------------------------------------------------------------
__device__ __forceinline__ float inter_term(float r0, float r1, float r2,
    float m01, float m02, float m10, float m12, float m20, float m21) {
  float mult = (m01 + m10) * (r0 * r1) + (m02 + m20) * (r0 * r2) + (m12 + m21) * (r1 * r2);
  float i0 = (r0 > 0.f) ? 1.f : 0.f;
  float i1 = (r1 > 0.f) ? 1.f : 0.f;
  float i2 = (r2 > 0.f) ? 1.f : 0.f;
  float cond = m01 * i0 * r1 + m02 * i0 * r2
             + m10 * i1 * r0 + m12 * i1 * r2
             + m20 * i2 * r0 + m21 * i2 * r1;
  float a = 0.6f * mult + 0.4f * cond;
  return (a == 0.0f) ? 0.0f : tanhf(a);
}

// ---------------------------------------------------------------------------
// PASS 1 (streaming): M = sum_r w_r*A_r (bf16); P = M + s*tanh(...) (bf16)
// A reads are nontemporal (448 MB, never reused) to keep L2/L3 for P/M/F.
// ---------------------------------------------------------------------------
__global__ __launch_bounds__(256) void k_pass1(
    const float* __restrict__ A, const float* __restrict__ wb,
    const float* __restrict__ Mri, const float* __restrict__ strength,
    unsigned short* __restrict__ P, unsigned short* __restrict__ Mm)
{
  const int row = blockIdx.x;
  const size_t off = (size_t)row * NDIM + threadIdx.x * 16;

  float w[7];
#pragma unroll
  for (int r = 0; r < 7; ++r) w[r] = wb[r];
  const float m01 = Mri[1], m02 = Mri[2], m10 = Mri[3];
  const float m12 = Mri[5], m20 = Mri[6], m21 = Mri[7];
  const float s = strength[0];

  f32x4 acc[4] = {};
  f32x4 rv[3][4];
#pragma unroll
  for (int r = 0; r < 7; ++r) {
    const float* Ar = A + (size_t)r * NNSZ + off;
#pragma unroll
    for (int q = 0; q < 4; ++q) {
      f32x4 v = __builtin_nontemporal_load((const f32x4*)(Ar + q * 4));
      acc[q].x = fmaf(w[r], v.x, acc[q].x);
      acc[q].y = fmaf(w[r], v.y, acc[q].y);
      acc[q].z = fmaf(w[r], v.z, acc[q].z);
      acc[q].w = fmaf(w[r], v.w, acc[q].w);
      if (r < 3) rv[r][q] = v;
    }
  }

  unsigned short pv[16], mv[16];
#pragma unroll
  for (int q = 0; q < 4; ++q) {
    float a0 = acc[q].x, a1 = acc[q].y, a2 = acc[q].z, a3 = acc[q].w;
    float t0 = inter_term(rv[0][q].x, rv[1][q].x, rv[2][q].x, m01, m02, m10, m12, m20, m21);
    float t1 = inter_term(rv[0][q].y, rv[1][q].y, rv[2][q].y, m01, m02, m10, m12, m20, m21);
    float t2 = inter_term(rv[0][q].z, rv[1][q].z, rv[2][q].z, m01, m02, m10, m12, m20, m21);
    float t3 = inter_term(rv[0][q].w, rv[1][q].w, rv[2][q].w, m01, m02, m10, m12, m20, m21);
    mv[q * 4 + 0] = f2bf(a0); pv[q * 4 + 0] = f2bf(fmaf(s, t0, a0));
    mv[q * 4 + 1] = f2bf(a1); pv[q * 4 + 1] = f2bf(fmaf(s, t1, a1));
    mv[q * 4 + 2] = f2bf(a2); pv[q * 4 + 2] = f2bf(fmaf(s, t2, a2));
    mv[q * 4 + 3] = f2bf(a3); pv[q * 4 + 3] = f2bf(fmaf(s, t3, a3));
  }
  *(uint4*)(P + off)      = ((const uint4*)pv)[0];
  *(uint4*)(P + off + 8)  = ((const uint4*)pv)[1];
  *(uint4*)(Mm + off)     = ((const uint4*)mv)[0];
  *(uint4*)(Mm + off + 8) = ((const uint4*)mv)[1];
}

// ---------------------------------------------------------------------------
// PASS 2: F = P + M^T. Conflict-free LDS transpose (stride 65 ushorts).
// ---------------------------------------------------------------------------
__global__ __launch_bounds__(256) void k_pass2(
    const unsigned short* __restrict__ P, const unsigned short* __restrict__ Mm,
    unsigned short* __restrict__ F)
{
  const int bi = blockIdx.x, bj = blockIdx.y;
  __shared__ unsigned short t[64 * 65];
  const int x  = threadIdx.x >> 2;          // 0..63
  const int y0 = (threadIdx.x & 3) << 4;    // 0,16,32,48

  const size_t moff = (size_t)(bj * 64 + x) * NDIM + bi * 64 + y0;
  unsigned short mv[16];
  ((uint4*)mv)[0] = *(const uint4*)(Mm + moff);
  ((uint4*)mv)[1] = *(const uint4*)(Mm + moff + 8);
#pragma unroll
  for (int e = 0; e < 16; ++e) t[x * 65 + y0 + e] = mv[e];
  __syncthreads();

  const size_t off = (size_t)(bi * 64 + x) * NDIM + bj * 64 + y0;
  unsigned short pv[16], ov[16];
  ((uint4*)pv)[0] = *(const uint4*)(P + off);
  ((uint4*)pv)[1] = *(const uint4*)(P + off + 8);
#pragma unroll
  for (int e = 0; e < 16; ++e)
    ov[e] = f2bf(bf2f(pv[e]) + bf2f(t[(y0 + e) * 65 + x]));
  *(uint4*)(F + off)     = ((const uint4*)ov)[0];
  *(uint4*)(F + off + 8) = ((const uint4*)ov)[1];
}

// ---------------------------------------------------------------------------
// k_z1t: Z1 = feature @ W1 (f32) AND Z1t = Z1^T (bf16), fused.
// 64 blocks x 256 thr; wave g owns rows n0+g*16..+15; lane j = col.
// Block 0 also zeroes the small accumulator region (1024 floats).
// ---------------------------------------------------------------------------
__global__ __launch_bounds__(256) void k_z1t(const float* __restrict__ feat,
    const float* __restrict__ W1, float* __restrict__ Z1,
    unsigned short* __restrict__ Z1t, float* __restrict__ small_zero) {
  if (blockIdx.x == 0) {
#pragma unroll
    for (int i = 0; i < 4; ++i) small_zero[threadIdx.x + i * 256] = 0.f;
  }
  const int n0 = blockIdx.x * 64;
  const int j = threadIdx.x & 63;
  const int g = __builtin_amdgcn_readfirstlane(threadIdx.x >> 6);  // wave-uniform
  const float* frow = feat + (size_t)(n0 + g * 16) * 128;

  float acc[16] = {};
  for (int k4 = 0; k4 < 128; k4 += 4) {
    float w0 = W1[(k4 + 0) * 64 + j];
    float w1 = W1[(k4 + 1) * 64 + j];
    float w2 = W1[(k4 + 2) * 64 + j];
    float w3 = W1[(k4 + 3) * 64 + j];
#pragma unroll
    for (int i = 0; i < 16; ++i) {
      float4 f = *(const float4*)(frow + i * 128 + k4);
      acc[i] = fmaf(f.x, w0, fmaf(f.y, w1, fmaf(f.z, w2, fmaf(f.w, w3, acc[i]))));
    }
  }
  unsigned short ov[16];
#pragma unroll
  for (int i = 0; i < 16; ++i) {
    Z1[(size_t)(n0 + g * 16 + i) * 64 + j] = acc[i];
    ov[i] = f2bf(acc[i]);
  }
  *(uint4*)(Z1t + (size_t)j * NDIM + n0 + g * 16)     = ((const uint4*)ov)[0];
  *(uint4*)(Z1t + (size_t)j * NDIM + n0 + g * 16 + 8) = ((const uint4*)ov)[1];
}

// ---------------------------------------------------------------------------
// U = F(bf16) @ Z (via Zt bf16) + bias  -> fp32.  mfma_f32_16x16x32_bf16.
// ---------------------------------------------------------------------------
__global__ __launch_bounds__(512) void k_mfma_gemm(
    const unsigned short* __restrict__ Fb,
    const unsigned short* __restrict__ Zt,
    const float* __restrict__ bias,
    float* __restrict__ U)
{
  __shared__ float red[8][16][66];
  const int strip = blockIdx.x * 16;
  const int w = threadIdx.x >> 6;
  const int lane = threadIdx.x & 63;
  const int arow = lane & 15;
  const int kq = lane >> 4;
  const int k_base = w * 512;

  f32x4 acc[4] = {};
  const unsigned short* Ap  = Fb + (size_t)(strip + arow) * NDIM + k_base + kq * 8;
  const unsigned short* Bp0 = Zt + (size_t)(arow) * NDIM + k_base + kq * 8;
  const unsigned short* Bp1 = Bp0 + (size_t)16 * NDIM;
  const unsigned short* Bp2 = Bp0 + (size_t)32 * NDIM;
  const unsigned short* Bp3 = Bp0 + (size_t)48 * NDIM;

#pragma unroll 4
  for (int step = 0; step < 16; ++step) {
    const int k0 = step * 32;
    short8 a  = *(const short8*)(Ap  + k0);
    short8 b0 = *(const short8*)(Bp0 + k0);
    short8 b1v = *(const short8*)(Bp1 + k0);
    short8 b2v = *(const short8*)(Bp2 + k0);
    short8 b3v = *(const short8*)(Bp3 + k0);
    acc[0] = __builtin_amdgcn_mfma_f32_16x16x32_bf16(a, b0,  acc[0], 0, 0, 0);
    acc[1] = __builtin_amdgcn_mfma_f32_16x16x32_bf16(a, b1v, acc[1], 0, 0, 0);
    acc[2] = __builtin_amdgcn_mfma_f32_16x16x32_bf16(a, b2v, acc[2], 0, 0, 0);
    acc[3] = __builtin_amdgcn_mfma_f32_16x16x32_bf16(a, b3v, acc[3], 0, 0, 0);
  }
#pragma unroll
  for (int t = 0; t < 4; ++t)
#pragma unroll
    for (int r = 0; r < 4; ++r)
      red[w][kq * 4 + r][t * 16 + arow] = acc[t][r];
  __syncthreads();

  const int col = threadIdx.x & 63;
  const int row0 = threadIdx.x >> 6;
#pragma unroll
  for (int rr = 0; rr < 2; ++rr) {
    const int row = row0 + rr * 8;
    float sum = 0.f;
#pragma unroll
    for (int ww = 0; ww < 8; ++ww) sum += red[ww][row][col];
    U[(size_t)(strip + row) * 64 + col] = sum + bias[col];
  }
}

// ---------------------------------------------------------------------------
__device__ __forceinline__ float wave_sum64(float v) {
#pragma unroll
  for (int o = 32; o > 0; o >>= 1) v += __shfl_xor(v, o, 64);
  return v;
}

// ---------------------------------------------------------------------------
// gemm2 + final epilogue: U2 = F@Z2 + b2; branch1=(U1+U2)/2;
// U4 = E*sw @ G2 + b2; result=(branch1+U4)/2; l2-normalize all three.
// ---------------------------------------------------------------------------
__global__ __launch_bounds__(512) void k_gemm2f(
    const unsigned short* __restrict__ Fb,
    const unsigned short* __restrict__ Zt,
    const float* __restrict__ b2,
    const float* __restrict__ U1,
    const float* __restrict__ encode,
    const float* __restrict__ sw,
    const float* __restrict__ G2,
    float* __restrict__ out)
{
  __shared__ float red[8][16][66];
  const int strip = blockIdx.x * 16;
  const int w = threadIdx.x >> 6;
  const int lane = threadIdx.x & 63;
  const int arow = lane & 15;
  const int kq = lane >> 4;
  const int k_base = w * 512;

  f32x4 acc[4] = {};
  const unsigned short* Ap  = Fb + (size_t)(strip + arow) * NDIM + k_base + kq * 8;
  const unsigned short* Bp0 = Zt + (size_t)(arow) * NDIM + k_base + kq * 8;
  const unsigned short* Bp1 = Bp0 + (size_t)16 * NDIM;
  const unsigned short* Bp2 = Bp0 + (size_t)32 * NDIM;
  const unsigned short* Bp3 = Bp0 + (size_t)48 * NDIM;

#pragma unroll 4
  for (int step = 0; step < 16; ++step) {
    const int k0 = step * 32;
    short8 a  = *(const short8*)(Ap  + k0);
    short8 b0 = *(const short8*)(Bp0 + k0);
    short8 b1v = *(const short8*)(Bp1 + k0);
    short8 b2v = *(const short8*)(Bp2 + k0);
    short8 b3v = *(const short8*)(Bp3 + k0);
    acc[0] = __builtin_amdgcn_mfma_f32_16x16x32_bf16(a, b0,  acc[0], 0, 0, 0);
    acc[1] = __builtin_amdgcn_mfma_f32_16x16x32_bf16(a, b1v, acc[1], 0, 0, 0);
    acc[2] = __builtin_amdgcn_mfma_f32_16x16x32_bf16(a, b2v, acc[2], 0, 0, 0);
    acc[3] = __builtin_amdgcn_mfma_f32_16x16x32_bf16(a, b3v, acc[3], 0, 0, 0);
  }
#pragma unroll
  for (int t = 0; t < 4; ++t)
#pragma unroll
    for (int r = 0; r < 4; ++r)
      red[w][kq * 4 + r][t * 16 + arow] = acc[t][r];
  __syncthreads();

  const int col = threadIdx.x & 63;
  const int row0 = threadIdx.x >> 6;
#pragma unroll
  for (int rr = 0; rr < 2; ++rr) {
    const int row = row0 + rr * 8;
    const int n = strip + row;
    float sum = 0.f;
#pragma unroll
    for (int ww = 0; ww < 8; ++ww) sum += red[ww][row][col];
    float u2 = sum + b2[col];
    float u1 = U1[(size_t)n * 64 + col];
    float br = 0.5f * (u1 + u2);
    float u4 = b2[col];
#pragma unroll
    for (int r = 0; r < 7; ++r)
      u4 = fmaf(encode[n * 7 + r] * sw[r], G2[r * 64 + col], u4);
    float rs = 0.5f * (br + u4);
    float nr = fmaxf(sqrtf(wave_sum64(rs * rs)), 1e-12f);
    float nb = fmaxf(sqrtf(wave_sum64(br * br)), 1e-12f);
    float nu = fmaxf(sqrtf(wave_sum64(u4 * u4)), 1e-12f);
    size_t idx = (size_t)n * 64 + col;
    out[idx] = rs / nr;
    out[(size_t)NDIM * 64 + idx] = br / nb;
    out[2 * (size_t)NDIM * 64 + idx] = u4 / nu;
  }
}

// ---------------------------------------------------------------------------
// Z2t[64][4096] bf16 = (U1 @ W2)^T
// ---------------------------------------------------------------------------
__global__ __launch_bounds__(256) void k_z2t(const float* __restrict__ U1,
    const float* __restrict__ W2, unsigned short* __restrict__ Z2t) {
  __shared__ float W2s[64][65];
  const int n0 = blockIdx.x * 64;
  const int j = threadIdx.x & 63;
  const int g = threadIdx.x >> 6;
  for (int r = g; r < 64; r += 4) W2s[r][j] = W2[r * 64 + j];
  __syncthreads();
  float acc[16];
#pragma unroll
  for (int r = 0; r < 16; ++r) acc[r] = 0.f;
  const float* Urow = U1 + (size_t)(n0 + g * 16) * 64;
  for (int k = 0; k < 64; ++k) {
    float wv = W2s[k][j];
#pragma unroll
    for (int r = 0; r < 16; ++r) acc[r] = fmaf(Urow[r * 64 + k], wv, acc[r]);
  }
  unsigned short ov[16];
#pragma unroll
  for (int r = 0; r < 16; ++r) ov[r] = f2bf(acc[r]);
  *(uint4*)(Z2t + (size_t)j * NDIM + n0 + g * 16)     = *(const uint4*)&ov[0];
  *(uint4*)(Z2t + (size_t)j * NDIM + n0 + g * 16 + 8) = *(const uint4*)&ov[8];
}

// ---------------------------------------------------------------------------
// S = E^T @ (E*sw)  (7x7),  c = colsum(E)  (7) — wave butterfly reduction
// ---------------------------------------------------------------------------
__global__ __launch_bounds__(256) void k_sc(const float* __restrict__ encode,
    const float* __restrict__ sw, float* __restrict__ S, float* __restrict__ c) {
  __shared__ float red[4][56];
  float sl[49], cl[7];
#pragma unroll
  for (int i = 0; i < 49; ++i) sl[i] = 0.f;
#pragma unroll
  for (int i = 0; i < 7; ++i) cl[i] = 0.f;
  for (int n = threadIdx.x; n < NDIM; n += 256) {
    float e[7];
#pragma unroll
    for (int r = 0; r < 7; ++r) e[r] = encode[n * 7 + r];
#pragma unroll
    for (int i = 0; i < 7; ++i) {
      cl[i] += e[i];
#pragma unroll
      for (int j = 0; j < 7; ++j) sl[i * 7 + j] = fmaf(e[i], e[j], sl[i * 7 + j]);
    }
  }
  const int lane = threadIdx.x & 63;
  const int w = threadIdx.x >> 6;
#pragma unroll
  for (int i = 0; i < 49; ++i) {
#pragma unroll
    for (int o = 32; o > 0; o >>= 1) sl[i] += __shfl_xor(sl[i], o, 64);
  }
#pragma unroll
  for (int i = 0; i < 7; ++i) {
#pragma unroll
    for (int o = 32; o > 0; o >>= 1) cl[i] += __shfl_xor(cl[i], o, 64);
  }
  if (lane == 0) {
#pragma unroll
    for (int i = 0; i < 49; ++i) red[w][i] = sl[i];
#pragma unroll
    for (int i = 0; i < 7; ++i) red[w][49 + i] = cl[i];
  }
  __syncthreads();
  if (threadIdx.x < 49)
    S[threadIdx.x] = (red[0][threadIdx.x] + red[1][threadIdx.x] + red[2][threadIdx.x] + red[3][threadIdx.x]) * sw[threadIdx.x % 7];
  if (threadIdx.x >= 49 && threadIdx.x < 56) {
    int i = threadIdx.x;
    c[i - 49] = red[0][i] + red[1][i] + red[2][i] + red[3][i];
  }
}

// ---------------------------------------------------------------------------
// G1 = E^T @ Z1  (7x64)
// ---------------------------------------------------------------------------
__global__ __launch_bounds__(256) void k_g1(const float* __restrict__ encode,
    const float* __restrict__ Z1, float* __restrict__ G1) {
  const int j = threadIdx.x & 63;
  const int grp = threadIdx.x >> 6;
  const int n0 = blockIdx.x * 128 + grp * 32;
  float acc[7];
#pragma unroll
  for (int r = 0; r < 7; ++r) acc[r] = 0.f;
  for (int i = 0; i < 32; ++i) {
    int n = n0 + i;
    float z = Z1[(size_t)n * 64 + j];
#pragma unroll
    for (int r = 0; r < 7; ++r) acc[r] = fmaf(encode[n * 7 + r], z, acc[r]);
  }
#pragma unroll
  for (int r = 0; r < 7; ++r) atomicAdd(&G1[r * 64 + j], acc[r]);
}

// ---------------------------------------------------------------------------
// G2 = S @ (G1 @ W2) + c (x) (b1 @ W2)    (7x64)
// ---------------------------------------------------------------------------
__global__ __launch_bounds__(64) void k_g2(const float* __restrict__ S,
    const float* __restrict__ c, const float* __restrict__ G1,
    const float* __restrict__ W2, const float* __restrict__ b1,
    float* __restrict__ G2) {
  int j = threadIdx.x;
  float h = 0.f;
  for (int k = 0; k < 64; ++k) h = fmaf(b1[k], W2[k * 64 + j], h);
  float gw[7];
#pragma unroll
  for (int r = 0; r < 7; ++r) {
    float v = 0.f;
    for (int k = 0; k < 64; ++k) v = fmaf(G1[r * 64 + k], W2[k * 64 + j], v);
    gw[r] = v;
  }
#pragma unroll
  for (int r = 0; r < 7; ++r) {
    float v = c[r] * h;
#pragma unroll
    for (int q = 0; q < 7; ++q) v = fmaf(S[r * 7 + q], gw[q], v);
    G2[r * 64 + j] = v;
  }
}

// ---------------------------------------------------------------------------
extern "C" void kernel_launch(void* const* d_in, const int* in_sizes, int n_in,
                              void* d_out, int out_size, void* d_ws, size_t ws_size,
                              hipStream_t stream) {
  const float* feature  = (const float*)d_in[0];
  const float* A        = (const float*)d_in[1];
  const float* encode   = (const float*)d_in[2];
  const float* W1       = (const float*)d_in[3];
  const float* b1       = (const float*)d_in[4];
  const float* W2       = (const float*)d_in[5];
  const float* b2       = (const float*)d_in[6];
  const float* wb       = (const float*)d_in[7];
  const float* Mri      = (const float*)d_in[8];
  const float* strength = (const float*)d_in[9];
  const float* sw       = (const float*)d_in[10];
  float* out = (float*)d_out;

  const size_t NV = (size_t)NDIM * 64;
  unsigned short* P  = (unsigned short*)d_ws;   // NNSZ bf16
  unsigned short* Mm = P + NNSZ;                // NNSZ bf16
  unsigned short* Fb = Mm + NNSZ;               // NNSZ bf16
  float* Z1 = (float*)(Fb + NNSZ);              // NV f32
  float* U1 = Z1 + NV;
  float* U2 = U1 + NV;                          // (slot kept, unused)
  unsigned short* Z1t = (unsigned short*)(U2 + NV);  // NV bf16
  unsigned short* Z2t = Z1t + NV;                    // NV bf16
  float* G1 = (float*)(Z2t + NV);               // 448  (start of 1024-float small region)
  float* S  = G1 + 448;
  float* c  = S + 49;
  float* G2 = c + 7;

  hipLaunchKernelGGL(k_pass1, dim3(NDIM), dim3(256), 0, stream, A, wb, Mri, strength, P, Mm);
  hipLaunchKernelGGL(k_pass2, dim3(64, 64), dim3(256), 0, stream, P, Mm, Fb);
  hipLaunchKernelGGL(k_z1t, dim3(64), dim3(256), 0, stream, feature, W1, Z1, Z1t, G1);
  hipLaunchKernelGGL(k_sc, dim3(1), dim3(256), 0, stream, encode, sw, S, c);
  hipLaunchKernelGGL(k_g1, dim3(32), dim3(256), 0, stream, encode, Z1, G1);
  hipLaunchKernelGGL(k_g2, dim3(1), dim3(64), 0, stream, S, c, G1, W2, b1, G2);
  hipLaunchKernelGGL(k_mfma_gemm, dim3(NDIM / 16), dim3(512), 0, stream, Fb, Z1t, b1, U1);
  hipLaunchKernelGGL(k_z2t, dim3(64), dim3(256), 0, stream, U1, W2, Z2t);
  hipLaunchKernelGGL(k_gemm2f, dim3(NDIM / 16), dim3(512), 0, stream, Fb, Z2t, b2, U1, encode, sw, G2, out);
}

// Round 9
// 270.700 us; speedup vs baseline: 1.1207x; 1.1207x over previous
//
#include <hip/hip_runtime.h>
#include <math.h>

#define NDIM 4096
#define NNSZ ((size_t)NDIM*(size_t)NDIM)

typedef __attribute__((ext_vector_type(8))) short short8;
typedef __attribute__((ext_vector_type(4))) float f32x4;

// float -> bf16 RNE
__device__ __forceinline__ unsigned short f2bf(float x) {
  unsigned u = __float_as_uint(x);
  u += 0x7FFFu + ((u >> 16) & 1u);
  return (unsigned short)(u >> 16);
}
__device__ __forceinline__ float bf2f(unsigned short u) {
  return __uint_as_float(((unsigned)u) << 16);
}

// ---------------------------------------------------------------------------
// interaction term: tanh(0.6*mult + 0.4*cond) from relations 0..2 at one elem
// ---------------------------------------------------------------------------
__device__ __forceinline__ float inter_term(float r0, float r1, float r2,
    float m01, float m02, float m10, float m12, float m20, float m21) {
  float mult = (m01 + m10) * (r0 * r1) + (m02 + m20) * (r0 * r2) + (m12 + m21) * (r1 * r2);
  float i0 = (r0 > 0.f) ? 1.f : 0.f;
  float i1 = (r1 > 0.f) ? 1.f : 0.f;
  float i2 = (r2 > 0.f) ? 1.f : 0.f;
  float cond = m01 * i0 * r1 + m02 * i0 * r2
             + m10 * i1 * r0 + m12 * i1 * r2
             + m20 * i2 * r0 + m21 * i2 * r1;
  float a = 0.6f * mult + 0.4f * cond;
  return (a == 0.0f) ? 0.0f : tanhf(a);
}

// ---------------------------------------------------------------------------
// PASS 1 (streaming): M = sum_r w_r*A_r (bf16); P = M + s*tanh(...) (bf16)
// Plain float4 loads — NT hints measured −25% BW on this pattern (round 8).
// ---------------------------------------------------------------------------
__global__ __launch_bounds__(256) void k_pass1(
    const float* __restrict__ A, const float* __restrict__ wb,
    const float* __restrict__ Mri, const float* __restrict__ strength,
    unsigned short* __restrict__ P, unsigned short* __restrict__ Mm)
{
  const int row = blockIdx.x;
  const size_t off = (size_t)row * NDIM + threadIdx.x * 16;

  float w[7];
#pragma unroll
  for (int r = 0; r < 7; ++r) w[r] = wb[r];
  const float m01 = Mri[1], m02 = Mri[2], m10 = Mri[3];
  const float m12 = Mri[5], m20 = Mri[6], m21 = Mri[7];
  const float s = strength[0];

  float4 acc[4] = {};
  float4 rv[3][4];
#pragma unroll
  for (int r = 0; r < 7; ++r) {
    const float* Ar = A + (size_t)r * NNSZ + off;
#pragma unroll
    for (int q = 0; q < 4; ++q) {
      float4 v = *(const float4*)(Ar + q * 4);
      acc[q].x = fmaf(w[r], v.x, acc[q].x);
      acc[q].y = fmaf(w[r], v.y, acc[q].y);
      acc[q].z = fmaf(w[r], v.z, acc[q].z);
      acc[q].w = fmaf(w[r], v.w, acc[q].w);
      if (r < 3) rv[r][q] = v;
    }
  }

  unsigned short pv[16], mv[16];
#pragma unroll
  for (int q = 0; q < 4; ++q) {
    float a0 = acc[q].x, a1 = acc[q].y, a2 = acc[q].z, a3 = acc[q].w;
    float t0 = inter_term(rv[0][q].x, rv[1][q].x, rv[2][q].x, m01, m02, m10, m12, m20, m21);
    float t1 = inter_term(rv[0][q].y, rv[1][q].y, rv[2][q].y, m01, m02, m10, m12, m20, m21);
    float t2 = inter_term(rv[0][q].z, rv[1][q].z, rv[2][q].z, m01, m02, m10, m12, m20, m21);
    float t3 = inter_term(rv[0][q].w, rv[1][q].w, rv[2][q].w, m01, m02, m10, m12, m20, m21);
    mv[q * 4 + 0] = f2bf(a0); pv[q * 4 + 0] = f2bf(fmaf(s, t0, a0));
    mv[q * 4 + 1] = f2bf(a1); pv[q * 4 + 1] = f2bf(fmaf(s, t1, a1));
    mv[q * 4 + 2] = f2bf(a2); pv[q * 4 + 2] = f2bf(fmaf(s, t2, a2));
    mv[q * 4 + 3] = f2bf(a3); pv[q * 4 + 3] = f2bf(fmaf(s, t3, a3));
  }
  *(uint4*)(P + off)      = ((const uint4*)pv)[0];
  *(uint4*)(P + off + 8)  = ((const uint4*)pv)[1];
  *(uint4*)(Mm + off)     = ((const uint4*)mv)[0];
  *(uint4*)(Mm + off + 8) = ((const uint4*)mv)[1];
}

// ---------------------------------------------------------------------------
// PASS 2: F = P + M^T. Conflict-free LDS transpose (stride 65 ushorts).
// ---------------------------------------------------------------------------
__global__ __launch_bounds__(256) void k_pass2(
    const unsigned short* __restrict__ P, const unsigned short* __restrict__ Mm,
    unsigned short* __restrict__ F)
{
  const int bi = blockIdx.x, bj = blockIdx.y;
  __shared__ unsigned short t[64 * 65];
  const int x  = threadIdx.x >> 2;          // 0..63
  const int y0 = (threadIdx.x & 3) << 4;    // 0,16,32,48

  const size_t moff = (size_t)(bj * 64 + x) * NDIM + bi * 64 + y0;
  unsigned short mv[16];
  ((uint4*)mv)[0] = *(const uint4*)(Mm + moff);
  ((uint4*)mv)[1] = *(const uint4*)(Mm + moff + 8);
#pragma unroll
  for (int e = 0; e < 16; ++e) t[x * 65 + y0 + e] = mv[e];
  __syncthreads();

  const size_t off = (size_t)(bi * 64 + x) * NDIM + bj * 64 + y0;
  unsigned short pv[16], ov[16];
  ((uint4*)pv)[0] = *(const uint4*)(P + off);
  ((uint4*)pv)[1] = *(const uint4*)(P + off + 8);
#pragma unroll
  for (int e = 0; e < 16; ++e)
    ov[e] = f2bf(bf2f(pv[e]) + bf2f(t[(y0 + e) * 65 + x]));
  *(uint4*)(F + off)     = ((const uint4*)ov)[0];
  *(uint4*)(F + off + 8) = ((const uint4*)ov)[1];
}

// ---------------------------------------------------------------------------
// k_z1t: Z1 = feature @ W1 (f32) AND Z1t = Z1^T (bf16), fused.
// Block 0 also zeroes the small accumulator region (1024 floats).
// ---------------------------------------------------------------------------
__global__ __launch_bounds__(256) void k_z1t(const float* __restrict__ feat,
    const float* __restrict__ W1, float* __restrict__ Z1,
    unsigned short* __restrict__ Z1t, float* __restrict__ small_zero) {
  if (blockIdx.x == 0) {
#pragma unroll
    for (int i = 0; i < 4; ++i) small_zero[threadIdx.x + i * 256] = 0.f;
  }
  const int n0 = blockIdx.x * 64;
  const int j = threadIdx.x & 63;
  const int g = __builtin_amdgcn_readfirstlane(threadIdx.x >> 6);  // wave-uniform
  const float* frow = feat + (size_t)(n0 + g * 16) * 128;

  float acc[16] = {};
  for (int k4 = 0; k4 < 128; k4 += 4) {
    float w0 = W1[(k4 + 0) * 64 + j];
    float w1 = W1[(k4 + 1) * 64 + j];
    float w2 = W1[(k4 + 2) * 64 + j];
    float w3 = W1[(k4 + 3) * 64 + j];
#pragma unroll
    for (int i = 0; i < 16; ++i) {
      float4 f = *(const float4*)(frow + i * 128 + k4);
      acc[i] = fmaf(f.x, w0, fmaf(f.y, w1, fmaf(f.z, w2, fmaf(f.w, w3, acc[i]))));
    }
  }
  unsigned short ov[16];
#pragma unroll
  for (int i = 0; i < 16; ++i) {
    Z1[(size_t)(n0 + g * 16 + i) * 64 + j] = acc[i];
    ov[i] = f2bf(acc[i]);
  }
  *(uint4*)(Z1t + (size_t)j * NDIM + n0 + g * 16)     = ((const uint4*)ov)[0];
  *(uint4*)(Z1t + (size_t)j * NDIM + n0 + g * 16 + 8) = ((const uint4*)ov)[1];
}

// ---------------------------------------------------------------------------
// U = F(bf16) @ Z (via Zt bf16) + bias  -> fp32.  mfma_f32_16x16x32_bf16.
// ---------------------------------------------------------------------------
__global__ __launch_bounds__(512) void k_mfma_gemm(
    const unsigned short* __restrict__ Fb,
    const unsigned short* __restrict__ Zt,
    const float* __restrict__ bias,
    float* __restrict__ U)
{
  __shared__ float red[8][16][66];
  const int strip = blockIdx.x * 16;
  const int w = threadIdx.x >> 6;
  const int lane = threadIdx.x & 63;
  const int arow = lane & 15;
  const int kq = lane >> 4;
  const int k_base = w * 512;

  f32x4 acc[4] = {};
  const unsigned short* Ap  = Fb + (size_t)(strip + arow) * NDIM + k_base + kq * 8;
  const unsigned short* Bp0 = Zt + (size_t)(arow) * NDIM + k_base + kq * 8;
  const unsigned short* Bp1 = Bp0 + (size_t)16 * NDIM;
  const unsigned short* Bp2 = Bp0 + (size_t)32 * NDIM;
  const unsigned short* Bp3 = Bp0 + (size_t)48 * NDIM;

#pragma unroll 4
  for (int step = 0; step < 16; ++step) {
    const int k0 = step * 32;
    short8 a  = *(const short8*)(Ap  + k0);
    short8 b0 = *(const short8*)(Bp0 + k0);
    short8 b1v = *(const short8*)(Bp1 + k0);
    short8 b2v = *(const short8*)(Bp2 + k0);
    short8 b3v = *(const short8*)(Bp3 + k0);
    acc[0] = __builtin_amdgcn_mfma_f32_16x16x32_bf16(a, b0,  acc[0], 0, 0, 0);
    acc[1] = __builtin_amdgcn_mfma_f32_16x16x32_bf16(a, b1v, acc[1], 0, 0, 0);
    acc[2] = __builtin_amdgcn_mfma_f32_16x16x32_bf16(a, b2v, acc[2], 0, 0, 0);
    acc[3] = __builtin_amdgcn_mfma_f32_16x16x32_bf16(a, b3v, acc[3], 0, 0, 0);
  }
#pragma unroll
  for (int t = 0; t < 4; ++t)
#pragma unroll
    for (int r = 0; r < 4; ++r)
      red[w][kq * 4 + r][t * 16 + arow] = acc[t][r];
  __syncthreads();

  const int col = threadIdx.x & 63;
  const int row0 = threadIdx.x >> 6;
#pragma unroll
  for (int rr = 0; rr < 2; ++rr) {
    const int row = row0 + rr * 8;
    float sum = 0.f;
#pragma unroll
    for (int ww = 0; ww < 8; ++ww) sum += red[ww][row][col];
    U[(size_t)(strip + row) * 64 + col] = sum + bias[col];
  }
}

// ---------------------------------------------------------------------------
__device__ __forceinline__ float wave_sum64(float v) {
#pragma unroll
  for (int o = 32; o > 0; o >>= 1) v += __shfl_xor(v, o, 64);
  return v;
}

// ---------------------------------------------------------------------------
// gemm2 + final epilogue: U2 = F@Z2 + b2; branch1=(U1+U2)/2;
// U4 = E*sw @ G2 + b2; result=(branch1+U4)/2; l2-normalize all three.
// ---------------------------------------------------------------------------
__global__ __launch_bounds__(512) void k_gemm2f(
    const unsigned short* __restrict__ Fb,
    const unsigned short* __restrict__ Zt,
    const float* __restrict__ b2,
    const float* __restrict__ U1,
    const float* __restrict__ encode,
    const float* __restrict__ sw,
    const float* __restrict__ G2,
    float* __restrict__ out)
{
  __shared__ float red[8][16][66];
  const int strip = blockIdx.x * 16;
  const int w = threadIdx.x >> 6;
  const int lane = threadIdx.x & 63;
  const int arow = lane & 15;
  const int kq = lane >> 4;
  const int k_base = w * 512;

  f32x4 acc[4] = {};
  const unsigned short* Ap  = Fb + (size_t)(strip + arow) * NDIM + k_base + kq * 8;
  const unsigned short* Bp0 = Zt + (size_t)(arow) * NDIM + k_base + kq * 8;
  const unsigned short* Bp1 = Bp0 + (size_t)16 * NDIM;
  const unsigned short* Bp2 = Bp0 + (size_t)32 * NDIM;
  const unsigned short* Bp3 = Bp0 + (size_t)48 * NDIM;

#pragma unroll 4
  for (int step = 0; step < 16; ++step) {
    const int k0 = step * 32;
    short8 a  = *(const short8*)(Ap  + k0);
    short8 b0 = *(const short8*)(Bp0 + k0);
    short8 b1v = *(const short8*)(Bp1 + k0);
    short8 b2v = *(const short8*)(Bp2 + k0);
    short8 b3v = *(const short8*)(Bp3 + k0);
    acc[0] = __builtin_amdgcn_mfma_f32_16x16x32_bf16(a, b0,  acc[0], 0, 0, 0);
    acc[1] = __builtin_amdgcn_mfma_f32_16x16x32_bf16(a, b1v, acc[1], 0, 0, 0);
    acc[2] = __builtin_amdgcn_mfma_f32_16x16x32_bf16(a, b2v, acc[2], 0, 0, 0);
    acc[3] = __builtin_amdgcn_mfma_f32_16x16x32_bf16(a, b3v, acc[3], 0, 0, 0);
  }
#pragma unroll
  for (int t = 0; t < 4; ++t)
#pragma unroll
    for (int r = 0; r < 4; ++r)
      red[w][kq * 4 + r][t * 16 + arow] = acc[t][r];
  __syncthreads();

  const int col = threadIdx.x & 63;
  const int row0 = threadIdx.x >> 6;
#pragma unroll
  for (int rr = 0; rr < 2; ++rr) {
    const int row = row0 + rr * 8;
    const int n = strip + row;
    float sum = 0.f;
#pragma unroll
    for (int ww = 0; ww < 8; ++ww) sum += red[ww][row][col];
    float u2 = sum + b2[col];
    float u1 = U1[(size_t)n * 64 + col];
    float br = 0.5f * (u1 + u2);
    float u4 = b2[col];
#pragma unroll
    for (int r = 0; r < 7; ++r)
      u4 = fmaf(encode[n * 7 + r] * sw[r], G2[r * 64 + col], u4);
    float rs = 0.5f * (br + u4);
    float nr = fmaxf(sqrtf(wave_sum64(rs * rs)), 1e-12f);
    float nb = fmaxf(sqrtf(wave_sum64(br * br)), 1e-12f);
    float nu = fmaxf(sqrtf(wave_sum64(u4 * u4)), 1e-12f);
    size_t idx = (size_t)n * 64 + col;
    out[idx] = rs / nr;
    out[(size_t)NDIM * 64 + idx] = br / nb;
    out[2 * (size_t)NDIM * 64 + idx] = u4 / nu;
  }
}

// ---------------------------------------------------------------------------
// Z2t[64][4096] bf16 = (U1 @ W2)^T
// ---------------------------------------------------------------------------
__global__ __launch_bounds__(256) void k_z2t(const float* __restrict__ U1,
    const float* __restrict__ W2, unsigned short* __restrict__ Z2t) {
  __shared__ float W2s[64][65];
  const int n0 = blockIdx.x * 64;
  const int j = threadIdx.x & 63;
  const int g = threadIdx.x >> 6;
  for (int r = g; r < 64; r += 4) W2s[r][j] = W2[r * 64 + j];
  __syncthreads();
  float acc[16];
#pragma unroll
  for (int r = 0; r < 16; ++r) acc[r] = 0.f;
  const float* Urow = U1 + (size_t)(n0 + g * 16) * 64;
  for (int k = 0; k < 64; ++k) {
    float wv = W2s[k][j];
#pragma unroll
    for (int r = 0; r < 16; ++r) acc[r] = fmaf(Urow[r * 64 + k], wv, acc[r]);
  }
  unsigned short ov[16];
#pragma unroll
  for (int r = 0; r < 16; ++r) ov[r] = f2bf(acc[r]);
  *(uint4*)(Z2t + (size_t)j * NDIM + n0 + g * 16)     = *(const uint4*)&ov[0];
  *(uint4*)(Z2t + (size_t)j * NDIM + n0 + g * 16 + 8) = *(const uint4*)&ov[8];
}

// ---------------------------------------------------------------------------
// S = E^T @ (E*sw)  (7x7),  c = colsum(E)  (7) — wave butterfly reduction
// ---------------------------------------------------------------------------
__global__ __launch_bounds__(256) void k_sc(const float* __restrict__ encode,
    const float* __restrict__ sw, float* __restrict__ S, float* __restrict__ c) {
  __shared__ float red[4][56];
  float sl[49], cl[7];
#pragma unroll
  for (int i = 0; i < 49; ++i) sl[i] = 0.f;
#pragma unroll
  for (int i = 0; i < 7; ++i) cl[i] = 0.f;
  for (int n = threadIdx.x; n < NDIM; n += 256) {
    float e[7];
#pragma unroll
    for (int r = 0; r < 7; ++r) e[r] = encode[n * 7 + r];
#pragma unroll
    for (int i = 0; i < 7; ++i) {
      cl[i] += e[i];
#pragma unroll
      for (int j = 0; j < 7; ++j) sl[i * 7 + j] = fmaf(e[i], e[j], sl[i * 7 + j]);
    }
  }
  const int lane = threadIdx.x & 63;
  const int w = threadIdx.x >> 6;
#pragma unroll
  for (int i = 0; i < 49; ++i) {
#pragma unroll
    for (int o = 32; o > 0; o >>= 1) sl[i] += __shfl_xor(sl[i], o, 64);
  }
#pragma unroll
  for (int i = 0; i < 7; ++i) {
#pragma unroll
    for (int o = 32; o > 0; o >>= 1) cl[i] += __shfl_xor(cl[i], o, 64);
  }
  if (lane == 0) {
#pragma unroll
    for (int i = 0; i < 49; ++i) red[w][i] = sl[i];
#pragma unroll
    for (int i = 0; i < 7; ++i) red[w][49 + i] = cl[i];
  }
  __syncthreads();
  if (threadIdx.x < 49)
    S[threadIdx.x] = (red[0][threadIdx.x] + red[1][threadIdx.x] + red[2][threadIdx.x] + red[3][threadIdx.x]) * sw[threadIdx.x % 7];
  if (threadIdx.x >= 49 && threadIdx.x < 56) {
    int i = threadIdx.x;
    c[i - 49] = red[0][i] + red[1][i] + red[2][i] + red[3][i];
  }
}

// ---------------------------------------------------------------------------
// G1 = E^T @ Z1  (7x64)
// ---------------------------------------------------------------------------
__global__ __launch_bounds__(256) void k_g1(const float* __restrict__ encode,
    const float* __restrict__ Z1, float* __restrict__ G1) {
  const int j = threadIdx.x & 63;
  const int grp = threadIdx.x >> 6;
  const int n0 = blockIdx.x * 128 + grp * 32;
  float acc[7];
#pragma unroll
  for (int r = 0; r < 7; ++r) acc[r] = 0.f;
  for (int i = 0; i < 32; ++i) {
    int n = n0 + i;
    float z = Z1[(size_t)n * 64 + j];
#pragma unroll
    for (int r = 0; r < 7; ++r) acc[r] = fmaf(encode[n * 7 + r], z, acc[r]);
  }
#pragma unroll
  for (int r = 0; r < 7; ++r) atomicAdd(&G1[r * 64 + j], acc[r]);
}

// ---------------------------------------------------------------------------
// G2 = S @ (G1 @ W2) + c (x) (b1 @ W2)    (7x64)
// ---------------------------------------------------------------------------
__global__ __launch_bounds__(64) void k_g2(const float* __restrict__ S,
    const float* __restrict__ c, const float* __restrict__ G1,
    const float* __restrict__ W2, const float* __restrict__ b1,
    float* __restrict__ G2) {
  int j = threadIdx.x;
  float h = 0.f;
  for (int k = 0; k < 64; ++k) h = fmaf(b1[k], W2[k * 64 + j], h);
  float gw[7];
#pragma unroll
  for (int r = 0; r < 7; ++r) {
    float v = 0.f;
    for (int k = 0; k < 64; ++k) v = fmaf(G1[r * 64 + k], W2[k * 64 + j], v);
    gw[r] = v;
  }
#pragma unroll
  for (int r = 0; r < 7; ++r) {
    float v = c[r] * h;
#pragma unroll
    for (int q = 0; q < 7; ++q) v = fmaf(S[r * 7 + q], gw[q], v);
    G2[r * 64 + j] = v;
  }
}

// ---------------------------------------------------------------------------
extern "C" void kernel_launch(void* const* d_in, const int* in_sizes, int n_in,
                              void* d_out, int out_size, void* d_ws, size_t ws_size,
                              hipStream_t stream) {
  const float* feature  = (const float*)d_in[0];
  const float* A        = (const float*)d_in[1];
  const float* encode   = (const float*)d_in[2];
  const float* W1       = (const float*)d_in[3];
  const float* b1       = (const float*)d_in[4];
  const float* W2       = (const float*)d_in[5];
  const float* b2       = (const float*)d_in[6];
  const float* wb       = (const float*)d_in[7];
  const float* Mri      = (const float*)d_in[8];
  const float* strength = (const float*)d_in[9];
  const float* sw       = (const float*)d_in[10];
  float* out = (float*)d_out;

  const size_t NV = (size_t)NDIM * 64;
  unsigned short* P  = (unsigned short*)d_ws;   // NNSZ bf16
  unsigned short* Mm = P + NNSZ;                // NNSZ bf16
  unsigned short* Fb = Mm + NNSZ;               // NNSZ bf16
  float* Z1 = (float*)(Fb + NNSZ);              // NV f32
  float* U1 = Z1 + NV;
  float* U2 = U1 + NV;                          // (slot kept, unused)
  unsigned short* Z1t = (unsigned short*)(U2 + NV);  // NV bf16
  unsigned short* Z2t = Z1t + NV;                    // NV bf16
  float* G1 = (float*)(Z2t + NV);               // 448  (start of 1024-float small region)
  float* S  = G1 + 448;
  float* c  = S + 49;
  float* G2 = c + 7;

  hipLaunchKernelGGL(k_pass1, dim3(NDIM), dim3(256), 0, stream, A, wb, Mri, strength, P, Mm);
  hipLaunchKernelGGL(k_pass2, dim3(64, 64), dim3(256), 0, stream, P, Mm, Fb);
  hipLaunchKernelGGL(k_z1t, dim3(64), dim3(256), 0, stream, feature, W1, Z1, Z1t, G1);
  hipLaunchKernelGGL(k_sc, dim3(1), dim3(256), 0, stream, encode, sw, S, c);
  hipLaunchKernelGGL(k_g1, dim3(32), dim3(256), 0, stream, encode, Z1, G1);
  hipLaunchKernelGGL(k_g2, dim3(1), dim3(64), 0, stream, S, c, G1, W2, b1, G2);
  hipLaunchKernelGGL(k_mfma_gemm, dim3(NDIM / 16), dim3(512), 0, stream, Fb, Z1t, b1, U1);
  hipLaunchKernelGGL(k_z2t, dim3(64), dim3(256), 0, stream, U1, W2, Z2t);
  hipLaunchKernelGGL(k_gemm2f, dim3(NDIM / 16), dim3(512), 0, stream, Fb, Z2t, b2, U1, encode, sw, G2, out);
}

// Round 10
// 247.301 us; speedup vs baseline: 1.2267x; 1.0946x over previous
//
#include <hip/hip_runtime.h>
#include <math.h>

#define NDIM 4096
#define NNSZ ((size_t)NDIM*(size_t)NDIM)

typedef __attribute__((ext_vector_type(8))) short short8;
typedef __attribute__((ext_vector_type(4))) float f32x4;

// float -> bf16 RNE
__device__ __forceinline__ unsigned short f2bf(float x) {
  unsigned u = __float_as_uint(x);
  u += 0x7FFFu + ((u >> 16) & 1u);
  return (unsigned short)(u >> 16);
}
__device__ __forceinline__ float bf2f(unsigned short u) {
  return __uint_as_float(((unsigned)u) << 16);
}

// ---------------------------------------------------------------------------
// interaction term: tanh(0.6*mult + 0.4*cond) from relations 0..2 at one elem
// ---------------------------------------------------------------------------
__device__ __forceinline__ float inter_term(float r0, float r1, float r2,
    float m01, float m02, float m10, float m12, float m20, float m21) {
  float mult = (m01 + m10) * (r0 * r1) + (m02 + m20) * (r0 * r2) + (m12 + m21) * (r1 * r2);
  float i0 = (r0 > 0.f) ? 1.f : 0.f;
  float i1 = (r1 > 0.f) ? 1.f : 0.f;
  float i2 = (r2 > 0.f) ? 1.f : 0.f;
  float cond = m01 * i0 * r1 + m02 * i0 * r2
             + m10 * i1 * r0 + m12 * i1 * r2
             + m20 * i2 * r0 + m21 * i2 * r1;
  float a = 0.6f * mult + 0.4f * cond;
  return (a == 0.0f) ? 0.0f : tanhf(a);
}

// ---------------------------------------------------------------------------
// PASS 1 (streaming): M = sum_r w_r*A_r (bf16); P = M + s*tanh(...) (bf16)
// Coalesced mapping: per q, thread tid owns float4 at (q*256+tid)*4 —
// every wave load is 1 KB contiguous, every store 512 B contiguous.
// (Old mapping: lanes 64 B apart -> 4 KB span/instr, L1 thrash at 112 KB/blk.)
// ---------------------------------------------------------------------------
__global__ __launch_bounds__(256) void k_pass1(
    const float* __restrict__ A, const float* __restrict__ wb,
    const float* __restrict__ Mri, const float* __restrict__ strength,
    unsigned short* __restrict__ P, unsigned short* __restrict__ Mm)
{
  const int row = blockIdx.x;
  const int tid = threadIdx.x;
  const size_t rowoff = (size_t)row * NDIM;

  float w[7];
#pragma unroll
  for (int r = 0; r < 7; ++r) w[r] = wb[r];
  const float m01 = Mri[1], m02 = Mri[2], m10 = Mri[3];
  const float m12 = Mri[5], m20 = Mri[6], m21 = Mri[7];
  const float s = strength[0];

#pragma unroll
  for (int q = 0; q < 4; ++q) {
    const size_t off = rowoff + (size_t)(q * 1024) + tid * 4;
    float4 v[7];
#pragma unroll
    for (int r = 0; r < 7; ++r)
      v[r] = *(const float4*)(A + (size_t)r * NNSZ + off);

    float4 acc = make_float4(0.f, 0.f, 0.f, 0.f);
#pragma unroll
    for (int r = 0; r < 7; ++r) {
      acc.x = fmaf(w[r], v[r].x, acc.x);
      acc.y = fmaf(w[r], v[r].y, acc.y);
      acc.z = fmaf(w[r], v[r].z, acc.z);
      acc.w = fmaf(w[r], v[r].w, acc.w);
    }
    float t0 = inter_term(v[0].x, v[1].x, v[2].x, m01, m02, m10, m12, m20, m21);
    float t1 = inter_term(v[0].y, v[1].y, v[2].y, m01, m02, m10, m12, m20, m21);
    float t2 = inter_term(v[0].z, v[1].z, v[2].z, m01, m02, m10, m12, m20, m21);
    float t3 = inter_term(v[0].w, v[1].w, v[2].w, m01, m02, m10, m12, m20, m21);

    *(ushort4*)(Mm + off) = make_ushort4(f2bf(acc.x), f2bf(acc.y), f2bf(acc.z), f2bf(acc.w));
    *(ushort4*)(P + off)  = make_ushort4(f2bf(fmaf(s, t0, acc.x)), f2bf(fmaf(s, t1, acc.y)),
                                         f2bf(fmaf(s, t2, acc.z)), f2bf(fmaf(s, t3, acc.w)));
  }
}

// ---------------------------------------------------------------------------
// PASS 2: F = P + M^T. Conflict-free LDS transpose (stride 65 ushorts).
// ---------------------------------------------------------------------------
__global__ __launch_bounds__(256) void k_pass2(
    const unsigned short* __restrict__ P, const unsigned short* __restrict__ Mm,
    unsigned short* __restrict__ F)
{
  const int bi = blockIdx.x, bj = blockIdx.y;
  __shared__ unsigned short t[64 * 65];
  const int x  = threadIdx.x >> 2;          // 0..63
  const int y0 = (threadIdx.x & 3) << 4;    // 0,16,32,48

  const size_t moff = (size_t)(bj * 64 + x) * NDIM + bi * 64 + y0;
  unsigned short mv[16];
  ((uint4*)mv)[0] = *(const uint4*)(Mm + moff);
  ((uint4*)mv)[1] = *(const uint4*)(Mm + moff + 8);
#pragma unroll
  for (int e = 0; e < 16; ++e) t[x * 65 + y0 + e] = mv[e];
  __syncthreads();

  const size_t off = (size_t)(bi * 64 + x) * NDIM + bj * 64 + y0;
  unsigned short pv[16], ov[16];
  ((uint4*)pv)[0] = *(const uint4*)(P + off);
  ((uint4*)pv)[1] = *(const uint4*)(P + off + 8);
#pragma unroll
  for (int e = 0; e < 16; ++e)
    ov[e] = f2bf(bf2f(pv[e]) + bf2f(t[(y0 + e) * 65 + x]));
  *(uint4*)(F + off)     = ((const uint4*)ov)[0];
  *(uint4*)(F + off + 8) = ((const uint4*)ov)[1];
}

// ---------------------------------------------------------------------------
// Z1 = feature @ W1   (4096x128 @ 128x64) fp32
// ---------------------------------------------------------------------------
__global__ __launch_bounds__(64) void k_z1(const float* __restrict__ feat,
    const float* __restrict__ W1, float* __restrict__ Z1) {
  int n = blockIdx.x, j = threadIdx.x;
  __shared__ float fr[128];
  fr[j] = feat[n * 128 + j];
  fr[j + 64] = feat[n * 128 + 64 + j];
  __syncthreads();
  float acc = 0.f;
#pragma unroll 8
  for (int k = 0; k < 128; ++k) acc = fmaf(fr[k], W1[k * 64 + j], acc);
  Z1[(size_t)n * 64 + j] = acc;
}

// ---------------------------------------------------------------------------
// Zt[64][4096] bf16  <-  Z[4096][64] fp32   (transpose + convert)
// ---------------------------------------------------------------------------
__global__ __launch_bounds__(256) void k_transpose_bf16(
    const float* __restrict__ Z, unsigned short* __restrict__ Zt) {
  __shared__ float tile[64][65];
  const int n0 = blockIdx.x * 64;
  const int c = threadIdx.x & 63;
  const int r0 = threadIdx.x >> 6;
#pragma unroll
  for (int i = 0; i < 16; ++i) {
    int r = r0 * 16 + i;
    tile[r][c] = Z[(size_t)(n0 + r) * 64 + c];
  }
  __syncthreads();
#pragma unroll
  for (int i = 0; i < 16; ++i) {
    int j = r0 * 16 + i;
    Zt[(size_t)j * NDIM + n0 + c] = f2bf(tile[c][j]);
  }
}

// ---------------------------------------------------------------------------
// U = F(bf16) @ Z (via Zt bf16) + bias  -> fp32.  mfma_f32_16x16x32_bf16.
// ---------------------------------------------------------------------------
__global__ __launch_bounds__(512) void k_mfma_gemm(
    const unsigned short* __restrict__ Fb,
    const unsigned short* __restrict__ Zt,
    const float* __restrict__ bias,
    float* __restrict__ U)
{
  __shared__ float red[8][16][66];
  const int strip = blockIdx.x * 16;
  const int w = threadIdx.x >> 6;
  const int lane = threadIdx.x & 63;
  const int arow = lane & 15;
  const int kq = lane >> 4;
  const int k_base = w * 512;

  f32x4 acc[4] = {};
  const unsigned short* Ap  = Fb + (size_t)(strip + arow) * NDIM + k_base + kq * 8;
  const unsigned short* Bp0 = Zt + (size_t)(arow) * NDIM + k_base + kq * 8;
  const unsigned short* Bp1 = Bp0 + (size_t)16 * NDIM;
  const unsigned short* Bp2 = Bp0 + (size_t)32 * NDIM;
  const unsigned short* Bp3 = Bp0 + (size_t)48 * NDIM;

#pragma unroll 4
  for (int step = 0; step < 16; ++step) {
    const int k0 = step * 32;
    short8 a  = *(const short8*)(Ap  + k0);
    short8 b0 = *(const short8*)(Bp0 + k0);
    short8 b1v = *(const short8*)(Bp1 + k0);
    short8 b2v = *(const short8*)(Bp2 + k0);
    short8 b3v = *(const short8*)(Bp3 + k0);
    acc[0] = __builtin_amdgcn_mfma_f32_16x16x32_bf16(a, b0,  acc[0], 0, 0, 0);
    acc[1] = __builtin_amdgcn_mfma_f32_16x16x32_bf16(a, b1v, acc[1], 0, 0, 0);
    acc[2] = __builtin_amdgcn_mfma_f32_16x16x32_bf16(a, b2v, acc[2], 0, 0, 0);
    acc[3] = __builtin_amdgcn_mfma_f32_16x16x32_bf16(a, b3v, acc[3], 0, 0, 0);
  }
#pragma unroll
  for (int t = 0; t < 4; ++t)
#pragma unroll
    for (int r = 0; r < 4; ++r)
      red[w][kq * 4 + r][t * 16 + arow] = acc[t][r];
  __syncthreads();

  const int col = threadIdx.x & 63;
  const int row0 = threadIdx.x >> 6;
#pragma unroll
  for (int rr = 0; rr < 2; ++rr) {
    const int row = row0 + rr * 8;
    float sum = 0.f;
#pragma unroll
    for (int ww = 0; ww < 8; ++ww) sum += red[ww][row][col];
    U[(size_t)(strip + row) * 64 + col] = sum + bias[col];
  }
}

// ---------------------------------------------------------------------------
__device__ __forceinline__ float wave_sum64(float v) {
#pragma unroll
  for (int o = 32; o > 0; o >>= 1) v += __shfl_xor(v, o, 64);
  return v;
}

// ---------------------------------------------------------------------------
// gemm2 + final epilogue: U2 = F@Z2 + b2; branch1=(U1+U2)/2;
// U4 = E*sw @ G2 + b2; result=(branch1+U4)/2; l2-normalize all three.
// ---------------------------------------------------------------------------
__global__ __launch_bounds__(512) void k_gemm2f(
    const unsigned short* __restrict__ Fb,
    const unsigned short* __restrict__ Zt,
    const float* __restrict__ b2,
    const float* __restrict__ U1,
    const float* __restrict__ encode,
    const float* __restrict__ sw,
    const float* __restrict__ G2,
    float* __restrict__ out)
{
  __shared__ float red[8][16][66];
  const int strip = blockIdx.x * 16;
  const int w = threadIdx.x >> 6;
  const int lane = threadIdx.x & 63;
  const int arow = lane & 15;
  const int kq = lane >> 4;
  const int k_base = w * 512;

  f32x4 acc[4] = {};
  const unsigned short* Ap  = Fb + (size_t)(strip + arow) * NDIM + k_base + kq * 8;
  const unsigned short* Bp0 = Zt + (size_t)(arow) * NDIM + k_base + kq * 8;
  const unsigned short* Bp1 = Bp0 + (size_t)16 * NDIM;
  const unsigned short* Bp2 = Bp0 + (size_t)32 * NDIM;
  const unsigned short* Bp3 = Bp0 + (size_t)48 * NDIM;

#pragma unroll 4
  for (int step = 0; step < 16; ++step) {
    const int k0 = step * 32;
    short8 a  = *(const short8*)(Ap  + k0);
    short8 b0 = *(const short8*)(Bp0 + k0);
    short8 b1v = *(const short8*)(Bp1 + k0);
    short8 b2v = *(const short8*)(Bp2 + k0);
    short8 b3v = *(const short8*)(Bp3 + k0);
    acc[0] = __builtin_amdgcn_mfma_f32_16x16x32_bf16(a, b0,  acc[0], 0, 0, 0);
    acc[1] = __builtin_amdgcn_mfma_f32_16x16x32_bf16(a, b1v, acc[1], 0, 0, 0);
    acc[2] = __builtin_amdgcn_mfma_f32_16x16x32_bf16(a, b2v, acc[2], 0, 0, 0);
    acc[3] = __builtin_amdgcn_mfma_f32_16x16x32_bf16(a, b3v, acc[3], 0, 0, 0);
  }
#pragma unroll
  for (int t = 0; t < 4; ++t)
#pragma unroll
    for (int r = 0; r < 4; ++r)
      red[w][kq * 4 + r][t * 16 + arow] = acc[t][r];
  __syncthreads();

  const int col = threadIdx.x & 63;
  const int row0 = threadIdx.x >> 6;
#pragma unroll
  for (int rr = 0; rr < 2; ++rr) {
    const int row = row0 + rr * 8;
    const int n = strip + row;
    float sum = 0.f;
#pragma unroll
    for (int ww = 0; ww < 8; ++ww) sum += red[ww][row][col];
    float u2 = sum + b2[col];
    float u1 = U1[(size_t)n * 64 + col];
    float br = 0.5f * (u1 + u2);
    float u4 = b2[col];
#pragma unroll
    for (int r = 0; r < 7; ++r)
      u4 = fmaf(encode[n * 7 + r] * sw[r], G2[r * 64 + col], u4);
    float rs = 0.5f * (br + u4);
    float nr = fmaxf(sqrtf(wave_sum64(rs * rs)), 1e-12f);
    float nb = fmaxf(sqrtf(wave_sum64(br * br)), 1e-12f);
    float nu = fmaxf(sqrtf(wave_sum64(u4 * u4)), 1e-12f);
    size_t idx = (size_t)n * 64 + col;
    out[idx] = rs / nr;
    out[(size_t)NDIM * 64 + idx] = br / nb;
    out[2 * (size_t)NDIM * 64 + idx] = u4 / nu;
  }
}

// ---------------------------------------------------------------------------
// Z2t[64][4096] bf16 = (U1 @ W2)^T
// ---------------------------------------------------------------------------
__global__ __launch_bounds__(256) void k_z2t(const float* __restrict__ U1,
    const float* __restrict__ W2, unsigned short* __restrict__ Z2t) {
  __shared__ float W2s[64][65];
  const int n0 = blockIdx.x * 64;
  const int j = threadIdx.x & 63;
  const int g = threadIdx.x >> 6;
  for (int r = g; r < 64; r += 4) W2s[r][j] = W2[r * 64 + j];
  __syncthreads();
  float acc[16];
#pragma unroll
  for (int r = 0; r < 16; ++r) acc[r] = 0.f;
  const float* Urow = U1 + (size_t)(n0 + g * 16) * 64;
  for (int k = 0; k < 64; ++k) {
    float wv = W2s[k][j];
#pragma unroll
    for (int r = 0; r < 16; ++r) acc[r] = fmaf(Urow[r * 64 + k], wv, acc[r]);
  }
  unsigned short ov[16];
#pragma unroll
  for (int r = 0; r < 16; ++r) ov[r] = f2bf(acc[r]);
  *(uint4*)(Z2t + (size_t)j * NDIM + n0 + g * 16)     = *(const uint4*)&ov[0];
  *(uint4*)(Z2t + (size_t)j * NDIM + n0 + g * 16 + 8) = *(const uint4*)&ov[8];
}

// ---------------------------------------------------------------------------
__global__ __launch_bounds__(512) void k_zero_small(float* __restrict__ g) {
  int t = threadIdx.x;
  if (t < 448) g[t] = 0.f;
}

// ---------------------------------------------------------------------------
// S = E^T @ (E*sw)  (7x7),  c = colsum(E)  (7) — wave butterfly reduction
// ---------------------------------------------------------------------------
__global__ __launch_bounds__(256) void k_sc(const float* __restrict__ encode,
    const float* __restrict__ sw, float* __restrict__ S, float* __restrict__ c) {
  __shared__ float red[4][56];
  float sl[49], cl[7];
#pragma unroll
  for (int i = 0; i < 49; ++i) sl[i] = 0.f;
#pragma unroll
  for (int i = 0; i < 7; ++i) cl[i] = 0.f;
  for (int n = threadIdx.x; n < NDIM; n += 256) {
    float e[7];
#pragma unroll
    for (int r = 0; r < 7; ++r) e[r] = encode[n * 7 + r];
#pragma unroll
    for (int i = 0; i < 7; ++i) {
      cl[i] += e[i];
#pragma unroll
      for (int j = 0; j < 7; ++j) sl[i * 7 + j] = fmaf(e[i], e[j], sl[i * 7 + j]);
    }
  }
  const int lane = threadIdx.x & 63;
  const int w = threadIdx.x >> 6;
#pragma unroll
  for (int i = 0; i < 49; ++i) {
#pragma unroll
    for (int o = 32; o > 0; o >>= 1) sl[i] += __shfl_xor(sl[i], o, 64);
  }
#pragma unroll
  for (int i = 0; i < 7; ++i) {
#pragma unroll
    for (int o = 32; o > 0; o >>= 1) cl[i] += __shfl_xor(cl[i], o, 64);
  }
  if (lane == 0) {
#pragma unroll
    for (int i = 0; i < 49; ++i) red[w][i] = sl[i];
#pragma unroll
    for (int i = 0; i < 7; ++i) red[w][49 + i] = cl[i];
  }
  __syncthreads();
  if (threadIdx.x < 49)
    S[threadIdx.x] = (red[0][threadIdx.x] + red[1][threadIdx.x] + red[2][threadIdx.x] + red[3][threadIdx.x]) * sw[threadIdx.x % 7];
  if (threadIdx.x >= 49 && threadIdx.x < 56) {
    int i = threadIdx.x;
    c[i - 49] = red[0][i] + red[1][i] + red[2][i] + red[3][i];
  }
}

// ---------------------------------------------------------------------------
// G1 = E^T @ Z1  (7x64)
// ---------------------------------------------------------------------------
__global__ __launch_bounds__(256) void k_g1(const float* __restrict__ encode,
    const float* __restrict__ Z1, float* __restrict__ G1) {
  const int j = threadIdx.x & 63;
  const int grp = threadIdx.x >> 6;
  const int n0 = blockIdx.x * 128 + grp * 32;
  float acc[7];
#pragma unroll
  for (int r = 0; r < 7; ++r) acc[r] = 0.f;
  for (int i = 0; i < 32; ++i) {
    int n = n0 + i;
    float z = Z1[(size_t)n * 64 + j];
#pragma unroll
    for (int r = 0; r < 7; ++r) acc[r] = fmaf(encode[n * 7 + r], z, acc[r]);
  }
#pragma unroll
  for (int r = 0; r < 7; ++r) atomicAdd(&G1[r * 64 + j], acc[r]);
}

// ---------------------------------------------------------------------------
// G2 = S @ (G1 @ W2) + c (x) (b1 @ W2)    (7x64)
// ---------------------------------------------------------------------------
__global__ __launch_bounds__(64) void k_g2(const float* __restrict__ S,
    const float* __restrict__ c, const float* __restrict__ G1,
    const float* __restrict__ W2, const float* __restrict__ b1,
    float* __restrict__ G2) {
  int j = threadIdx.x;
  float h = 0.f;
  for (int k = 0; k < 64; ++k) h = fmaf(b1[k], W2[k * 64 + j], h);
  float gw[7];
#pragma unroll
  for (int r = 0; r < 7; ++r) {
    float v = 0.f;
    for (int k = 0; k < 64; ++k) v = fmaf(G1[r * 64 + k], W2[k * 64 + j], v);
    gw[r] = v;
  }
#pragma unroll
  for (int r = 0; r < 7; ++r) {
    float v = c[r] * h;
#pragma unroll
    for (int q = 0; q < 7; ++q) v = fmaf(S[r * 7 + q], gw[q], v);
    G2[r * 64 + j] = v;
  }
}

// ---------------------------------------------------------------------------
extern "C" void kernel_launch(void* const* d_in, const int* in_sizes, int n_in,
                              void* d_out, int out_size, void* d_ws, size_t ws_size,
                              hipStream_t stream) {
  const float* feature  = (const float*)d_in[0];
  const float* A        = (const float*)d_in[1];
  const float* encode   = (const float*)d_in[2];
  const float* W1       = (const float*)d_in[3];
  const float* b1       = (const float*)d_in[4];
  const float* W2       = (const float*)d_in[5];
  const float* b2       = (const float*)d_in[6];
  const float* wb       = (const float*)d_in[7];
  const float* Mri      = (const float*)d_in[8];
  const float* strength = (const float*)d_in[9];
  const float* sw       = (const float*)d_in[10];
  float* out = (float*)d_out;

  const size_t NV = (size_t)NDIM * 64;
  unsigned short* P  = (unsigned short*)d_ws;   // NNSZ bf16
  unsigned short* Mm = P + NNSZ;                // NNSZ bf16
  unsigned short* Fb = Mm + NNSZ;               // NNSZ bf16
  float* Z1 = (float*)(Fb + NNSZ);              // NV f32
  float* U1 = Z1 + NV;
  float* U2 = U1 + NV;                          // (slot kept, unused)
  unsigned short* Z1t = (unsigned short*)(U2 + NV);  // NV bf16
  unsigned short* Z2t = Z1t + NV;                    // NV bf16
  float* G1 = (float*)(Z2t + NV);               // 448
  float* S  = G1 + 448;
  float* c  = S + 49;
  float* G2 = c + 7;

  hipLaunchKernelGGL(k_zero_small, dim3(1), dim3(512), 0, stream, G1);
  hipLaunchKernelGGL(k_pass1, dim3(NDIM), dim3(256), 0, stream, A, wb, Mri, strength, P, Mm);
  hipLaunchKernelGGL(k_pass2, dim3(64, 64), dim3(256), 0, stream, P, Mm, Fb);
  hipLaunchKernelGGL(k_z1, dim3(NDIM), dim3(64), 0, stream, feature, W1, Z1);
  hipLaunchKernelGGL(k_transpose_bf16, dim3(64), dim3(256), 0, stream, Z1, Z1t);
  hipLaunchKernelGGL(k_sc, dim3(1), dim3(256), 0, stream, encode, sw, S, c);
  hipLaunchKernelGGL(k_g1, dim3(32), dim3(256), 0, stream, encode, Z1, G1);
  hipLaunchKernelGGL(k_g2, dim3(1), dim3(64), 0, stream, S, c, G1, W2, b1, G2);
  hipLaunchKernelGGL(k_mfma_gemm, dim3(NDIM / 16), dim3(512), 0, stream, Fb, Z1t, b1, U1);
  hipLaunchKernelGGL(k_z2t, dim3(64), dim3(256), 0, stream, U1, W2, Z2t);
  hipLaunchKernelGGL(k_gemm2f, dim3(NDIM / 16), dim3(512), 0, stream, Fb, Z2t, b2, U1, encode, sw, G2, out);
}

// Round 11
// 243.211 us; speedup vs baseline: 1.2474x; 1.0168x over previous
//
#include <hip/hip_runtime.h>
#include <math.h>

#define NDIM 4096
#define NNSZ ((size_t)NDIM*(size_t)NDIM)
#define SCAP 262144u

typedef __attribute__((ext_vector_type(8))) short short8;
typedef __attribute__((ext_vector_type(4))) float f32x4;

// float -> bf16 RNE
__device__ __forceinline__ unsigned short f2bf(float x) {
  unsigned u = __float_as_uint(x);
  u += 0x7FFFu + ((u >> 16) & 1u);
  return (unsigned short)(u >> 16);
}
__device__ __forceinline__ float bf2f(unsigned short u) {
  return __uint_as_float(((unsigned)u) << 16);
}

// ---------------------------------------------------------------------------
// interaction term: tanh(0.6*mult + 0.4*cond) from relations 0..2 at one elem
// Nonzero ONLY when >=2 of {r0,r1,r2} are nonzero (all terms are pair
// products r_u*r_v or indicator(r_u)*r_v, u!=v).
// ---------------------------------------------------------------------------
__device__ __forceinline__ float inter_term(float r0, float r1, float r2,
    float m01, float m02, float m10, float m12, float m20, float m21) {
  float mult = (m01 + m10) * (r0 * r1) + (m02 + m20) * (r0 * r2) + (m12 + m21) * (r1 * r2);
  float i0 = (r0 > 0.f) ? 1.f : 0.f;
  float i1 = (r1 > 0.f) ? 1.f : 0.f;
  float i2 = (r2 > 0.f) ? 1.f : 0.f;
  float cond = m01 * i0 * r1 + m02 * i0 * r2
             + m10 * i1 * r0 + m12 * i1 * r2
             + m20 * i2 * r0 + m21 * i2 * r1;
  float a = 0.6f * mult + 0.4f * cond;
  return (a == 0.0f) ? 0.0f : tanhf(a);
}

// ---------------------------------------------------------------------------
// PASS 1 (streaming): Mm = sum_r w_r*A_r (bf16). The interaction term is
// ~5K nonzeros out of 16.7M -> emitted as sparse (pos, s*T) pairs instead of
// a dense 64 MB P buffer. (NT-load hint measured -25% BW here — round 8.)
// ---------------------------------------------------------------------------
__global__ __launch_bounds__(256) void k_pass1(
    const float* __restrict__ A, const float* __restrict__ wb,
    const float* __restrict__ Mri, const float* __restrict__ strength,
    unsigned short* __restrict__ Mm, unsigned* __restrict__ sidx,
    float* __restrict__ sval, unsigned* __restrict__ scnt)
{
  const int row = blockIdx.x;
  const int tid = threadIdx.x;
  const size_t rowoff = (size_t)row * NDIM;

  float w[7];
#pragma unroll
  for (int r = 0; r < 7; ++r) w[r] = wb[r];
  const float m01 = Mri[1], m02 = Mri[2], m10 = Mri[3];
  const float m12 = Mri[5], m20 = Mri[6], m21 = Mri[7];
  const float s = strength[0];

#pragma unroll
  for (int q = 0; q < 4; ++q) {
    const size_t off = rowoff + (size_t)(q * 1024) + tid * 4;
    float4 v[7];
#pragma unroll
    for (int r = 0; r < 7; ++r)
      v[r] = *(const float4*)(A + (size_t)r * NNSZ + off);

    float4 acc = make_float4(0.f, 0.f, 0.f, 0.f);
#pragma unroll
    for (int r = 0; r < 7; ++r) {
      acc.x = fmaf(w[r], v[r].x, acc.x);
      acc.y = fmaf(w[r], v[r].y, acc.y);
      acc.z = fmaf(w[r], v[r].z, acc.z);
      acc.w = fmaf(w[r], v[r].w, acc.w);
    }
    *(ushort4*)(Mm + off) = make_ushort4(f2bf(acc.x), f2bf(acc.y), f2bf(acc.z), f2bf(acc.w));

    // sparse interaction emit (rare: needs >=2 of r0,r1,r2 nonzero)
    {
      float r0 = v[0].x, r1 = v[1].x, r2 = v[2].x;
      if ((int)(r0 != 0.f) + (int)(r1 != 0.f) + (int)(r2 != 0.f) >= 2) {
        float t = inter_term(r0, r1, r2, m01, m02, m10, m12, m20, m21);
        unsigned idx = atomicAdd(scnt, 1u);
        if (idx < SCAP) { sidx[idx] = (unsigned)(off + 0); sval[idx] = s * t; }
      }
    }
    {
      float r0 = v[0].y, r1 = v[1].y, r2 = v[2].y;
      if ((int)(r0 != 0.f) + (int)(r1 != 0.f) + (int)(r2 != 0.f) >= 2) {
        float t = inter_term(r0, r1, r2, m01, m02, m10, m12, m20, m21);
        unsigned idx = atomicAdd(scnt, 1u);
        if (idx < SCAP) { sidx[idx] = (unsigned)(off + 1); sval[idx] = s * t; }
      }
    }
    {
      float r0 = v[0].z, r1 = v[1].z, r2 = v[2].z;
      if ((int)(r0 != 0.f) + (int)(r1 != 0.f) + (int)(r2 != 0.f) >= 2) {
        float t = inter_term(r0, r1, r2, m01, m02, m10, m12, m20, m21);
        unsigned idx = atomicAdd(scnt, 1u);
        if (idx < SCAP) { sidx[idx] = (unsigned)(off + 2); sval[idx] = s * t; }
      }
    }
    {
      float r0 = v[0].w, r1 = v[1].w, r2 = v[2].w;
      if ((int)(r0 != 0.f) + (int)(r1 != 0.f) + (int)(r2 != 0.f) >= 2) {
        float t = inter_term(r0, r1, r2, m01, m02, m10, m12, m20, m21);
        unsigned idx = atomicAdd(scnt, 1u);
        if (idx < SCAP) { sidx[idx] = (unsigned)(off + 3); sval[idx] = s * t; }
      }
    }
  }
}

// ---------------------------------------------------------------------------
// PASS 2: F = M + M^T (both reads from the single 64 MB M buffer).
// Conflict-free LDS transpose (stride 65 ushorts).
// ---------------------------------------------------------------------------
__global__ __launch_bounds__(256) void k_pass2(
    const unsigned short* __restrict__ Mm, unsigned short* __restrict__ F)
{
  const int bi = blockIdx.x, bj = blockIdx.y;
  __shared__ unsigned short t[64 * 65];
  const int x  = threadIdx.x >> 2;          // 0..63
  const int y0 = (threadIdx.x & 3) << 4;    // 0,16,32,48

  const size_t moff = (size_t)(bj * 64 + x) * NDIM + bi * 64 + y0;
  unsigned short mv[16];
  ((uint4*)mv)[0] = *(const uint4*)(Mm + moff);
  ((uint4*)mv)[1] = *(const uint4*)(Mm + moff + 8);
#pragma unroll
  for (int e = 0; e < 16; ++e) t[x * 65 + y0 + e] = mv[e];
  __syncthreads();

  const size_t off = (size_t)(bi * 64 + x) * NDIM + bj * 64 + y0;
  unsigned short pv[16], ov[16];
  ((uint4*)pv)[0] = *(const uint4*)(Mm + off);
  ((uint4*)pv)[1] = *(const uint4*)(Mm + off + 8);
#pragma unroll
  for (int e = 0; e < 16; ++e)
    ov[e] = f2bf(bf2f(pv[e]) + bf2f(t[(y0 + e) * 65 + x]));
  *(uint4*)(F + off)     = ((const uint4*)ov)[0];
  *(uint4*)(F + off + 8) = ((const uint4*)ov)[1];
}

// ---------------------------------------------------------------------------
// k_fix: scatter the sparse interaction into F. Distinct positions -> no race.
// ---------------------------------------------------------------------------
__global__ __launch_bounds__(256) void k_fix(const unsigned* __restrict__ sidx,
    const float* __restrict__ sval, const unsigned* __restrict__ scnt,
    unsigned short* __restrict__ F) {
  unsigned n = *scnt;
  if (n > SCAP) n = SCAP;
  for (unsigned i = blockIdx.x * 256 + threadIdx.x; i < n; i += gridDim.x * 256) {
    unsigned pos = sidx[i];
    F[pos] = f2bf(bf2f(F[pos]) + sval[i]);
  }
}

// ---------------------------------------------------------------------------
// Z1 = feature @ W1   (4096x128 @ 128x64) fp32
// ---------------------------------------------------------------------------
__global__ __launch_bounds__(64) void k_z1(const float* __restrict__ feat,
    const float* __restrict__ W1, float* __restrict__ Z1) {
  int n = blockIdx.x, j = threadIdx.x;
  __shared__ float fr[128];
  fr[j] = feat[n * 128 + j];
  fr[j + 64] = feat[n * 128 + 64 + j];
  __syncthreads();
  float acc = 0.f;
#pragma unroll 8
  for (int k = 0; k < 128; ++k) acc = fmaf(fr[k], W1[k * 64 + j], acc);
  Z1[(size_t)n * 64 + j] = acc;
}

// ---------------------------------------------------------------------------
// Zt[64][4096] bf16  <-  Z[4096][64] fp32   (transpose + convert)
// ---------------------------------------------------------------------------
__global__ __launch_bounds__(256) void k_transpose_bf16(
    const float* __restrict__ Z, unsigned short* __restrict__ Zt) {
  __shared__ float tile[64][65];
  const int n0 = blockIdx.x * 64;
  const int c = threadIdx.x & 63;
  const int r0 = threadIdx.x >> 6;
#pragma unroll
  for (int i = 0; i < 16; ++i) {
    int r = r0 * 16 + i;
    tile[r][c] = Z[(size_t)(n0 + r) * 64 + c];
  }
  __syncthreads();
#pragma unroll
  for (int i = 0; i < 16; ++i) {
    int j = r0 * 16 + i;
    Zt[(size_t)j * NDIM + n0 + c] = f2bf(tile[c][j]);
  }
}

// ---------------------------------------------------------------------------
// U = F(bf16) @ Z (via Zt bf16) + bias  -> fp32.  mfma_f32_16x16x32_bf16.
// ---------------------------------------------------------------------------
__global__ __launch_bounds__(512) void k_mfma_gemm(
    const unsigned short* __restrict__ Fb,
    const unsigned short* __restrict__ Zt,
    const float* __restrict__ bias,
    float* __restrict__ U)
{
  __shared__ float red[8][16][66];
  const int strip = blockIdx.x * 16;
  const int w = threadIdx.x >> 6;
  const int lane = threadIdx.x & 63;
  const int arow = lane & 15;
  const int kq = lane >> 4;
  const int k_base = w * 512;

  f32x4 acc[4] = {};
  const unsigned short* Ap  = Fb + (size_t)(strip + arow) * NDIM + k_base + kq * 8;
  const unsigned short* Bp0 = Zt + (size_t)(arow) * NDIM + k_base + kq * 8;
  const unsigned short* Bp1 = Bp0 + (size_t)16 * NDIM;
  const unsigned short* Bp2 = Bp0 + (size_t)32 * NDIM;
  const unsigned short* Bp3 = Bp0 + (size_t)48 * NDIM;

#pragma unroll 4
  for (int step = 0; step < 16; ++step) {
    const int k0 = step * 32;
    short8 a  = *(const short8*)(Ap  + k0);
    short8 b0 = *(const short8*)(Bp0 + k0);
    short8 b1v = *(const short8*)(Bp1 + k0);
    short8 b2v = *(const short8*)(Bp2 + k0);
    short8 b3v = *(const short8*)(Bp3 + k0);
    acc[0] = __builtin_amdgcn_mfma_f32_16x16x32_bf16(a, b0,  acc[0], 0, 0, 0);
    acc[1] = __builtin_amdgcn_mfma_f32_16x16x32_bf16(a, b1v, acc[1], 0, 0, 0);
    acc[2] = __builtin_amdgcn_mfma_f32_16x16x32_bf16(a, b2v, acc[2], 0, 0, 0);
    acc[3] = __builtin_amdgcn_mfma_f32_16x16x32_bf16(a, b3v, acc[3], 0, 0, 0);
  }
#pragma unroll
  for (int t = 0; t < 4; ++t)
#pragma unroll
    for (int r = 0; r < 4; ++r)
      red[w][kq * 4 + r][t * 16 + arow] = acc[t][r];
  __syncthreads();

  const int col = threadIdx.x & 63;
  const int row0 = threadIdx.x >> 6;
#pragma unroll
  for (int rr = 0; rr < 2; ++rr) {
    const int row = row0 + rr * 8;
    float sum = 0.f;
#pragma unroll
    for (int ww = 0; ww < 8; ++ww) sum += red[ww][row][col];
    U[(size_t)(strip + row) * 64 + col] = sum + bias[col];
  }
}

// ---------------------------------------------------------------------------
__device__ __forceinline__ float wave_sum64(float v) {
#pragma unroll
  for (int o = 32; o > 0; o >>= 1) v += __shfl_xor(v, o, 64);
  return v;
}

// ---------------------------------------------------------------------------
// gemm2 + final epilogue: U2 = F@Z2 + b2; branch1=(U1+U2)/2;
// U4 = E*sw @ G2 + b2; result=(branch1+U4)/2; l2-normalize all three.
// ---------------------------------------------------------------------------
__global__ __launch_bounds__(512) void k_gemm2f(
    const unsigned short* __restrict__ Fb,
    const unsigned short* __restrict__ Zt,
    const float* __restrict__ b2,
    const float* __restrict__ U1,
    const float* __restrict__ encode,
    const float* __restrict__ sw,
    const float* __restrict__ G2,
    float* __restrict__ out)
{
  __shared__ float red[8][16][66];
  const int strip = blockIdx.x * 16;
  const int w = threadIdx.x >> 6;
  const int lane = threadIdx.x & 63;
  const int arow = lane & 15;
  const int kq = lane >> 4;
  const int k_base = w * 512;

  f32x4 acc[4] = {};
  const unsigned short* Ap  = Fb + (size_t)(strip + arow) * NDIM + k_base + kq * 8;
  const unsigned short* Bp0 = Zt + (size_t)(arow) * NDIM + k_base + kq * 8;
  const unsigned short* Bp1 = Bp0 + (size_t)16 * NDIM;
  const unsigned short* Bp2 = Bp0 + (size_t)32 * NDIM;
  const unsigned short* Bp3 = Bp0 + (size_t)48 * NDIM;

#pragma unroll 4
  for (int step = 0; step < 16; ++step) {
    const int k0 = step * 32;
    short8 a  = *(const short8*)(Ap  + k0);
    short8 b0 = *(const short8*)(Bp0 + k0);
    short8 b1v = *(const short8*)(Bp1 + k0);
    short8 b2v = *(const short8*)(Bp2 + k0);
    short8 b3v = *(const short8*)(Bp3 + k0);
    acc[0] = __builtin_amdgcn_mfma_f32_16x16x32_bf16(a, b0,  acc[0], 0, 0, 0);
    acc[1] = __builtin_amdgcn_mfma_f32_16x16x32_bf16(a, b1v, acc[1], 0, 0, 0);
    acc[2] = __builtin_amdgcn_mfma_f32_16x16x32_bf16(a, b2v, acc[2], 0, 0, 0);
    acc[3] = __builtin_amdgcn_mfma_f32_16x16x32_bf16(a, b3v, acc[3], 0, 0, 0);
  }
#pragma unroll
  for (int t = 0; t < 4; ++t)
#pragma unroll
    for (int r = 0; r < 4; ++r)
      red[w][kq * 4 + r][t * 16 + arow] = acc[t][r];
  __syncthreads();

  const int col = threadIdx.x & 63;
  const int row0 = threadIdx.x >> 6;
#pragma unroll
  for (int rr = 0; rr < 2; ++rr) {
    const int row = row0 + rr * 8;
    const int n = strip + row;
    float sum = 0.f;
#pragma unroll
    for (int ww = 0; ww < 8; ++ww) sum += red[ww][row][col];
    float u2 = sum + b2[col];
    float u1 = U1[(size_t)n * 64 + col];
    float br = 0.5f * (u1 + u2);
    float u4 = b2[col];
#pragma unroll
    for (int r = 0; r < 7; ++r)
      u4 = fmaf(encode[n * 7 + r] * sw[r], G2[r * 64 + col], u4);
    float rs = 0.5f * (br + u4);
    float nr = fmaxf(sqrtf(wave_sum64(rs * rs)), 1e-12f);
    float nb = fmaxf(sqrtf(wave_sum64(br * br)), 1e-12f);
    float nu = fmaxf(sqrtf(wave_sum64(u4 * u4)), 1e-12f);
    size_t idx = (size_t)n * 64 + col;
    out[idx] = rs / nr;
    out[(size_t)NDIM * 64 + idx] = br / nb;
    out[2 * (size_t)NDIM * 64 + idx] = u4 / nu;
  }
}

// ---------------------------------------------------------------------------
// Z2t[64][4096] bf16 = (U1 @ W2)^T
// ---------------------------------------------------------------------------
__global__ __launch_bounds__(256) void k_z2t(const float* __restrict__ U1,
    const float* __restrict__ W2, unsigned short* __restrict__ Z2t) {
  __shared__ float W2s[64][65];
  const int n0 = blockIdx.x * 64;
  const int j = threadIdx.x & 63;
  const int g = threadIdx.x >> 6;
  for (int r = g; r < 64; r += 4) W2s[r][j] = W2[r * 64 + j];
  __syncthreads();
  float acc[16];
#pragma unroll
  for (int r = 0; r < 16; ++r) acc[r] = 0.f;
  const float* Urow = U1 + (size_t)(n0 + g * 16) * 64;
  for (int k = 0; k < 64; ++k) {
    float wv = W2s[k][j];
#pragma unroll
    for (int r = 0; r < 16; ++r) acc[r] = fmaf(Urow[r * 64 + k], wv, acc[r]);
  }
  unsigned short ov[16];
#pragma unroll
  for (int r = 0; r < 16; ++r) ov[r] = f2bf(acc[r]);
  *(uint4*)(Z2t + (size_t)j * NDIM + n0 + g * 16)     = *(const uint4*)&ov[0];
  *(uint4*)(Z2t + (size_t)j * NDIM + n0 + g * 16 + 8) = *(const uint4*)&ov[8];
}

// ---------------------------------------------------------------------------
__global__ __launch_bounds__(512) void k_zero_small(float* __restrict__ g,
    unsigned* __restrict__ scnt) {
  int t = threadIdx.x;
  if (t < 448) g[t] = 0.f;
  if (t == 448) *scnt = 0u;
}

// ---------------------------------------------------------------------------
// S = E^T @ (E*sw)  (7x7),  c = colsum(E)  (7) — wave butterfly reduction
// ---------------------------------------------------------------------------
__global__ __launch_bounds__(256) void k_sc(const float* __restrict__ encode,
    const float* __restrict__ sw, float* __restrict__ S, float* __restrict__ c) {
  __shared__ float red[4][56];
  float sl[49], cl[7];
#pragma unroll
  for (int i = 0; i < 49; ++i) sl[i] = 0.f;
#pragma unroll
  for (int i = 0; i < 7; ++i) cl[i] = 0.f;
  for (int n = threadIdx.x; n < NDIM; n += 256) {
    float e[7];
#pragma unroll
    for (int r = 0; r < 7; ++r) e[r] = encode[n * 7 + r];
#pragma unroll
    for (int i = 0; i < 7; ++i) {
      cl[i] += e[i];
#pragma unroll
      for (int j = 0; j < 7; ++j) sl[i * 7 + j] = fmaf(e[i], e[j], sl[i * 7 + j]);
    }
  }
  const int lane = threadIdx.x & 63;
  const int w = threadIdx.x >> 6;
#pragma unroll
  for (int i = 0; i < 49; ++i) {
#pragma unroll
    for (int o = 32; o > 0; o >>= 1) sl[i] += __shfl_xor(sl[i], o, 64);
  }
#pragma unroll
  for (int i = 0; i < 7; ++i) {
#pragma unroll
    for (int o = 32; o > 0; o >>= 1) cl[i] += __shfl_xor(cl[i], o, 64);
  }
  if (lane == 0) {
#pragma unroll
    for (int i = 0; i < 49; ++i) red[w][i] = sl[i];
#pragma unroll
    for (int i = 0; i < 7; ++i) red[w][49 + i] = cl[i];
  }
  __syncthreads();
  if (threadIdx.x < 49)
    S[threadIdx.x] = (red[0][threadIdx.x] + red[1][threadIdx.x] + red[2][threadIdx.x] + red[3][threadIdx.x]) * sw[threadIdx.x % 7];
  if (threadIdx.x >= 49 && threadIdx.x < 56) {
    int i = threadIdx.x;
    c[i - 49] = red[0][i] + red[1][i] + red[2][i] + red[3][i];
  }
}

// ---------------------------------------------------------------------------
// G1 = E^T @ Z1  (7x64)
// ---------------------------------------------------------------------------
__global__ __launch_bounds__(256) void k_g1(const float* __restrict__ encode,
    const float* __restrict__ Z1, float* __restrict__ G1) {
  const int j = threadIdx.x & 63;
  const int grp = threadIdx.x >> 6;
  const int n0 = blockIdx.x * 128 + grp * 32;
  float acc[7];
#pragma unroll
  for (int r = 0; r < 7; ++r) acc[r] = 0.f;
  for (int i = 0; i < 32; ++i) {
    int n = n0 + i;
    float z = Z1[(size_t)n * 64 + j];
#pragma unroll
    for (int r = 0; r < 7; ++r) acc[r] = fmaf(encode[n * 7 + r], z, acc[r]);
  }
#pragma unroll
  for (int r = 0; r < 7; ++r) atomicAdd(&G1[r * 64 + j], acc[r]);
}

// ---------------------------------------------------------------------------
// G2 = S @ (G1 @ W2) + c (x) (b1 @ W2)    (7x64)
// ---------------------------------------------------------------------------
__global__ __launch_bounds__(64) void k_g2(const float* __restrict__ S,
    const float* __restrict__ c, const float* __restrict__ G1,
    const float* __restrict__ W2, const float* __restrict__ b1,
    float* __restrict__ G2) {
  int j = threadIdx.x;
  float h = 0.f;
  for (int k = 0; k < 64; ++k) h = fmaf(b1[k], W2[k * 64 + j], h);
  float gw[7];
#pragma unroll
  for (int r = 0; r < 7; ++r) {
    float v = 0.f;
    for (int k = 0; k < 64; ++k) v = fmaf(G1[r * 64 + k], W2[k * 64 + j], v);
    gw[r] = v;
  }
#pragma unroll
  for (int r = 0; r < 7; ++r) {
    float v = c[r] * h;
#pragma unroll
    for (int q = 0; q < 7; ++q) v = fmaf(S[r * 7 + q], gw[q], v);
    G2[r * 64 + j] = v;
  }
}

// ---------------------------------------------------------------------------
extern "C" void kernel_launch(void* const* d_in, const int* in_sizes, int n_in,
                              void* d_out, int out_size, void* d_ws, size_t ws_size,
                              hipStream_t stream) {
  const float* feature  = (const float*)d_in[0];
  const float* A        = (const float*)d_in[1];
  const float* encode   = (const float*)d_in[2];
  const float* W1       = (const float*)d_in[3];
  const float* b1       = (const float*)d_in[4];
  const float* W2       = (const float*)d_in[5];
  const float* b2       = (const float*)d_in[6];
  const float* wb       = (const float*)d_in[7];
  const float* Mri      = (const float*)d_in[8];
  const float* strength = (const float*)d_in[9];
  const float* sw       = (const float*)d_in[10];
  float* out = (float*)d_out;

  const size_t NV = (size_t)NDIM * 64;
  // old P slot (32 MB) now holds the sparse arrays:
  unsigned* sidx = (unsigned*)d_ws;                       // SCAP u32
  float* sval = (float*)(sidx + SCAP);                    // SCAP f32
  unsigned* scnt = (unsigned*)(sval + SCAP);              // 1 u32
  unsigned short* Mm = (unsigned short*)d_ws + NNSZ;      // NNSZ bf16
  unsigned short* Fb = Mm + NNSZ;                         // NNSZ bf16
  float* Z1 = (float*)(Fb + NNSZ);                        // NV f32
  float* U1 = Z1 + NV;
  float* U2 = U1 + NV;                                    // (slot kept, unused)
  unsigned short* Z1t = (unsigned short*)(U2 + NV);       // NV bf16
  unsigned short* Z2t = Z1t + NV;                         // NV bf16
  float* G1 = (float*)(Z2t + NV);                         // 448
  float* S  = G1 + 448;
  float* c  = S + 49;
  float* G2 = c + 7;

  hipLaunchKernelGGL(k_zero_small, dim3(1), dim3(512), 0, stream, G1, scnt);
  hipLaunchKernelGGL(k_pass1, dim3(NDIM), dim3(256), 0, stream, A, wb, Mri, strength, Mm, sidx, sval, scnt);
  hipLaunchKernelGGL(k_pass2, dim3(64, 64), dim3(256), 0, stream, Mm, Fb);
  hipLaunchKernelGGL(k_fix, dim3(32), dim3(256), 0, stream, sidx, sval, scnt, Fb);
  hipLaunchKernelGGL(k_z1, dim3(NDIM), dim3(64), 0, stream, feature, W1, Z1);
  hipLaunchKernelGGL(k_transpose_bf16, dim3(64), dim3(256), 0, stream, Z1, Z1t);
  hipLaunchKernelGGL(k_sc, dim3(1), dim3(256), 0, stream, encode, sw, S, c);
  hipLaunchKernelGGL(k_g1, dim3(32), dim3(256), 0, stream, encode, Z1, G1);
  hipLaunchKernelGGL(k_g2, dim3(1), dim3(64), 0, stream, S, c, G1, W2, b1, G2);
  hipLaunchKernelGGL(k_mfma_gemm, dim3(NDIM / 16), dim3(512), 0, stream, Fb, Z1t, b1, U1);
  hipLaunchKernelGGL(k_z2t, dim3(64), dim3(256), 0, stream, U1, W2, Z2t);
  hipLaunchKernelGGL(k_gemm2f, dim3(NDIM / 16), dim3(512), 0, stream, Fb, Z2t, b2, U1, encode, sw, G2, out);
}

// Round 12
// 237.946 us; speedup vs baseline: 1.2750x; 1.0221x over previous
//
#include <hip/hip_runtime.h>
#include <math.h>

#define NDIM 4096
#define NNSZ ((size_t)NDIM*(size_t)NDIM)
#define SCAP 262144u

typedef __attribute__((ext_vector_type(8))) short short8;
typedef __attribute__((ext_vector_type(4))) float f32x4;

// float -> bf16 RNE
__device__ __forceinline__ unsigned short f2bf(float x) {
  unsigned u = __float_as_uint(x);
  u += 0x7FFFu + ((u >> 16) & 1u);
  return (unsigned short)(u >> 16);
}
__device__ __forceinline__ float bf2f(unsigned short u) {
  return __uint_as_float(((unsigned)u) << 16);
}

// ---------------------------------------------------------------------------
// interaction term: tanh(0.6*mult + 0.4*cond) from relations 0..2 at one elem
// Nonzero ONLY when >=2 of {r0,r1,r2} are nonzero.
// ---------------------------------------------------------------------------
__device__ __forceinline__ float inter_term(float r0, float r1, float r2,
    float m01, float m02, float m10, float m12, float m20, float m21) {
  float mult = (m01 + m10) * (r0 * r1) + (m02 + m20) * (r0 * r2) + (m12 + m21) * (r1 * r2);
  float i0 = (r0 > 0.f) ? 1.f : 0.f;
  float i1 = (r1 > 0.f) ? 1.f : 0.f;
  float i2 = (r2 > 0.f) ? 1.f : 0.f;
  float cond = m01 * i0 * r1 + m02 * i0 * r2
             + m10 * i1 * r0 + m12 * i1 * r2
             + m20 * i2 * r0 + m21 * i2 * r1;
  float a = 0.6f * mult + 0.4f * cond;
  return (a == 0.0f) ? 0.0f : tanhf(a);
}

// ---------------------------------------------------------------------------
// PASS 1 v3 (max-TLP): one float4 per thread, 16384 blocks. Each thread:
// 7 independent loads -> compute -> 1 store. __launch_bounds__(256,4) caps
// VGPR at 128 so >=16 waves/CU keep ~28 KB of loads in flight per CU.
// ---------------------------------------------------------------------------
__global__ __launch_bounds__(256, 4) void k_pass1(
    const float* __restrict__ A, const float* __restrict__ wb,
    const float* __restrict__ Mri, const float* __restrict__ strength,
    unsigned short* __restrict__ Mm, unsigned* __restrict__ sidx,
    float* __restrict__ sval, unsigned* __restrict__ scnt)
{
  const unsigned gid = blockIdx.x * 256 + threadIdx.x;
  const size_t off = (size_t)gid * 4;

  float w[7];
#pragma unroll
  for (int r = 0; r < 7; ++r) w[r] = wb[r];
  const float m01 = Mri[1], m02 = Mri[2], m10 = Mri[3];
  const float m12 = Mri[5], m20 = Mri[6], m21 = Mri[7];
  const float s = strength[0];

  float4 v[7];
#pragma unroll
  for (int r = 0; r < 7; ++r)
    v[r] = *(const float4*)(A + (size_t)r * NNSZ + off);

  float4 acc = make_float4(0.f, 0.f, 0.f, 0.f);
#pragma unroll
  for (int r = 0; r < 7; ++r) {
    acc.x = fmaf(w[r], v[r].x, acc.x);
    acc.y = fmaf(w[r], v[r].y, acc.y);
    acc.z = fmaf(w[r], v[r].z, acc.z);
    acc.w = fmaf(w[r], v[r].w, acc.w);
  }
  *(ushort4*)(Mm + off) = make_ushort4(f2bf(acc.x), f2bf(acc.y), f2bf(acc.z), f2bf(acc.w));

  // sparse interaction emit (rare: needs >=2 of r0,r1,r2 nonzero)
  {
    float r0 = v[0].x, r1 = v[1].x, r2 = v[2].x;
    if ((int)(r0 != 0.f) + (int)(r1 != 0.f) + (int)(r2 != 0.f) >= 2) {
      float t = inter_term(r0, r1, r2, m01, m02, m10, m12, m20, m21);
      unsigned idx = atomicAdd(scnt, 1u);
      if (idx < SCAP) { sidx[idx] = (unsigned)(off + 0); sval[idx] = s * t; }
    }
  }
  {
    float r0 = v[0].y, r1 = v[1].y, r2 = v[2].y;
    if ((int)(r0 != 0.f) + (int)(r1 != 0.f) + (int)(r2 != 0.f) >= 2) {
      float t = inter_term(r0, r1, r2, m01, m02, m10, m12, m20, m21);
      unsigned idx = atomicAdd(scnt, 1u);
      if (idx < SCAP) { sidx[idx] = (unsigned)(off + 1); sval[idx] = s * t; }
    }
  }
  {
    float r0 = v[0].z, r1 = v[1].z, r2 = v[2].z;
    if ((int)(r0 != 0.f) + (int)(r1 != 0.f) + (int)(r2 != 0.f) >= 2) {
      float t = inter_term(r0, r1, r2, m01, m02, m10, m12, m20, m21);
      unsigned idx = atomicAdd(scnt, 1u);
      if (idx < SCAP) { sidx[idx] = (unsigned)(off + 2); sval[idx] = s * t; }
    }
  }
  {
    float r0 = v[0].w, r1 = v[1].w, r2 = v[2].w;
    if ((int)(r0 != 0.f) + (int)(r1 != 0.f) + (int)(r2 != 0.f) >= 2) {
      float t = inter_term(r0, r1, r2, m01, m02, m10, m12, m20, m21);
      unsigned idx = atomicAdd(scnt, 1u);
      if (idx < SCAP) { sidx[idx] = (unsigned)(off + 3); sval[idx] = s * t; }
    }
  }
}

// ---------------------------------------------------------------------------
// PASS 2: F = M + M^T. Conflict-free LDS transpose (stride 65 ushorts).
// ---------------------------------------------------------------------------
__global__ __launch_bounds__(256) void k_pass2(
    const unsigned short* __restrict__ Mm, unsigned short* __restrict__ F)
{
  const int bi = blockIdx.x, bj = blockIdx.y;
  __shared__ unsigned short t[64 * 65];
  const int x  = threadIdx.x >> 2;          // 0..63
  const int y0 = (threadIdx.x & 3) << 4;    // 0,16,32,48

  const size_t moff = (size_t)(bj * 64 + x) * NDIM + bi * 64 + y0;
  unsigned short mv[16];
  ((uint4*)mv)[0] = *(const uint4*)(Mm + moff);
  ((uint4*)mv)[1] = *(const uint4*)(Mm + moff + 8);
#pragma unroll
  for (int e = 0; e < 16; ++e) t[x * 65 + y0 + e] = mv[e];
  __syncthreads();

  const size_t off = (size_t)(bi * 64 + x) * NDIM + bj * 64 + y0;
  unsigned short pv[16], ov[16];
  ((uint4*)pv)[0] = *(const uint4*)(Mm + off);
  ((uint4*)pv)[1] = *(const uint4*)(Mm + off + 8);
#pragma unroll
  for (int e = 0; e < 16; ++e)
    ov[e] = f2bf(bf2f(pv[e]) + bf2f(t[(y0 + e) * 65 + x]));
  *(uint4*)(F + off)     = ((const uint4*)ov)[0];
  *(uint4*)(F + off + 8) = ((const uint4*)ov)[1];
}

// ---------------------------------------------------------------------------
// k_fix: scatter the sparse interaction into F. Distinct positions -> no race.
// ---------------------------------------------------------------------------
__global__ __launch_bounds__(256) void k_fix(const unsigned* __restrict__ sidx,
    const float* __restrict__ sval, const unsigned* __restrict__ scnt,
    unsigned short* __restrict__ F) {
  unsigned n = *scnt;
  if (n > SCAP) n = SCAP;
  for (unsigned i = blockIdx.x * 256 + threadIdx.x; i < n; i += gridDim.x * 256) {
    unsigned pos = sidx[i];
    F[pos] = f2bf(bf2f(F[pos]) + sval[i]);
  }
}

// ---------------------------------------------------------------------------
// Z1 = feature @ W1   (4096x128 @ 128x64) fp32
// ---------------------------------------------------------------------------
__global__ __launch_bounds__(64) void k_z1(const float* __restrict__ feat,
    const float* __restrict__ W1, float* __restrict__ Z1) {
  int n = blockIdx.x, j = threadIdx.x;
  __shared__ float fr[128];
  fr[j] = feat[n * 128 + j];
  fr[j + 64] = feat[n * 128 + 64 + j];
  __syncthreads();
  float acc = 0.f;
#pragma unroll 8
  for (int k = 0; k < 128; ++k) acc = fmaf(fr[k], W1[k * 64 + j], acc);
  Z1[(size_t)n * 64 + j] = acc;
}

// ---------------------------------------------------------------------------
// Zt[64][4096] bf16  <-  Z[4096][64] fp32   (transpose + convert)
// ---------------------------------------------------------------------------
__global__ __launch_bounds__(256) void k_transpose_bf16(
    const float* __restrict__ Z, unsigned short* __restrict__ Zt) {
  __shared__ float tile[64][65];
  const int n0 = blockIdx.x * 64;
  const int c = threadIdx.x & 63;
  const int r0 = threadIdx.x >> 6;
#pragma unroll
  for (int i = 0; i < 16; ++i) {
    int r = r0 * 16 + i;
    tile[r][c] = Z[(size_t)(n0 + r) * 64 + c];
  }
  __syncthreads();
#pragma unroll
  for (int i = 0; i < 16; ++i) {
    int j = r0 * 16 + i;
    Zt[(size_t)j * NDIM + n0 + c] = f2bf(tile[c][j]);
  }
}

// ---------------------------------------------------------------------------
// U = F(bf16) @ Z (via Zt bf16) + bias  -> fp32.  mfma_f32_16x16x32_bf16.
// ---------------------------------------------------------------------------
__global__ __launch_bounds__(512) void k_mfma_gemm(
    const unsigned short* __restrict__ Fb,
    const unsigned short* __restrict__ Zt,
    const float* __restrict__ bias,
    float* __restrict__ U)
{
  __shared__ float red[8][16][66];
  const int strip = blockIdx.x * 16;
  const int w = threadIdx.x >> 6;
  const int lane = threadIdx.x & 63;
  const int arow = lane & 15;
  const int kq = lane >> 4;
  const int k_base = w * 512;

  f32x4 acc[4] = {};
  const unsigned short* Ap  = Fb + (size_t)(strip + arow) * NDIM + k_base + kq * 8;
  const unsigned short* Bp0 = Zt + (size_t)(arow) * NDIM + k_base + kq * 8;
  const unsigned short* Bp1 = Bp0 + (size_t)16 * NDIM;
  const unsigned short* Bp2 = Bp0 + (size_t)32 * NDIM;
  const unsigned short* Bp3 = Bp0 + (size_t)48 * NDIM;

#pragma unroll 4
  for (int step = 0; step < 16; ++step) {
    const int k0 = step * 32;
    short8 a  = *(const short8*)(Ap  + k0);
    short8 b0 = *(const short8*)(Bp0 + k0);
    short8 b1v = *(const short8*)(Bp1 + k0);
    short8 b2v = *(const short8*)(Bp2 + k0);
    short8 b3v = *(const short8*)(Bp3 + k0);
    acc[0] = __builtin_amdgcn_mfma_f32_16x16x32_bf16(a, b0,  acc[0], 0, 0, 0);
    acc[1] = __builtin_amdgcn_mfma_f32_16x16x32_bf16(a, b1v, acc[1], 0, 0, 0);
    acc[2] = __builtin_amdgcn_mfma_f32_16x16x32_bf16(a, b2v, acc[2], 0, 0, 0);
    acc[3] = __builtin_amdgcn_mfma_f32_16x16x32_bf16(a, b3v, acc[3], 0, 0, 0);
  }
#pragma unroll
  for (int t = 0; t < 4; ++t)
#pragma unroll
    for (int r = 0; r < 4; ++r)
      red[w][kq * 4 + r][t * 16 + arow] = acc[t][r];
  __syncthreads();

  const int col = threadIdx.x & 63;
  const int row0 = threadIdx.x >> 6;
#pragma unroll
  for (int rr = 0; rr < 2; ++rr) {
    const int row = row0 + rr * 8;
    float sum = 0.f;
#pragma unroll
    for (int ww = 0; ww < 8; ++ww) sum += red[ww][row][col];
    U[(size_t)(strip + row) * 64 + col] = sum + bias[col];
  }
}

// ---------------------------------------------------------------------------
__device__ __forceinline__ float wave_sum64(float v) {
#pragma unroll
  for (int o = 32; o > 0; o >>= 1) v += __shfl_xor(v, o, 64);
  return v;
}

// ---------------------------------------------------------------------------
// gemm2 + final epilogue: U2 = F@Z2 + b2; branch1=(U1+U2)/2;
// U4 = E*sw @ G2 + b2; result=(branch1+U4)/2; l2-normalize all three.
// ---------------------------------------------------------------------------
__global__ __launch_bounds__(512) void k_gemm2f(
    const unsigned short* __restrict__ Fb,
    const unsigned short* __restrict__ Zt,
    const float* __restrict__ b2,
    const float* __restrict__ U1,
    const float* __restrict__ encode,
    const float* __restrict__ sw,
    const float* __restrict__ G2,
    float* __restrict__ out)
{
  __shared__ float red[8][16][66];
  const int strip = blockIdx.x * 16;
  const int w = threadIdx.x >> 6;
  const int lane = threadIdx.x & 63;
  const int arow = lane & 15;
  const int kq = lane >> 4;
  const int k_base = w * 512;

  f32x4 acc[4] = {};
  const unsigned short* Ap  = Fb + (size_t)(strip + arow) * NDIM + k_base + kq * 8;
  const unsigned short* Bp0 = Zt + (size_t)(arow) * NDIM + k_base + kq * 8;
  const unsigned short* Bp1 = Bp0 + (size_t)16 * NDIM;
  const unsigned short* Bp2 = Bp0 + (size_t)32 * NDIM;
  const unsigned short* Bp3 = Bp0 + (size_t)48 * NDIM;

#pragma unroll 4
  for (int step = 0; step < 16; ++step) {
    const int k0 = step * 32;
    short8 a  = *(const short8*)(Ap  + k0);
    short8 b0 = *(const short8*)(Bp0 + k0);
    short8 b1v = *(const short8*)(Bp1 + k0);
    short8 b2v = *(const short8*)(Bp2 + k0);
    short8 b3v = *(const short8*)(Bp3 + k0);
    acc[0] = __builtin_amdgcn_mfma_f32_16x16x32_bf16(a, b0,  acc[0], 0, 0, 0);
    acc[1] = __builtin_amdgcn_mfma_f32_16x16x32_bf16(a, b1v, acc[1], 0, 0, 0);
    acc[2] = __builtin_amdgcn_mfma_f32_16x16x32_bf16(a, b2v, acc[2], 0, 0, 0);
    acc[3] = __builtin_amdgcn_mfma_f32_16x16x32_bf16(a, b3v, acc[3], 0, 0, 0);
  }
#pragma unroll
  for (int t = 0; t < 4; ++t)
#pragma unroll
    for (int r = 0; r < 4; ++r)
      red[w][kq * 4 + r][t * 16 + arow] = acc[t][r];
  __syncthreads();

  const int col = threadIdx.x & 63;
  const int row0 = threadIdx.x >> 6;
#pragma unroll
  for (int rr = 0; rr < 2; ++rr) {
    const int row = row0 + rr * 8;
    const int n = strip + row;
    float sum = 0.f;
#pragma unroll
    for (int ww = 0; ww < 8; ++ww) sum += red[ww][row][col];
    float u2 = sum + b2[col];
    float u1 = U1[(size_t)n * 64 + col];
    float br = 0.5f * (u1 + u2);
    float u4 = b2[col];
#pragma unroll
    for (int r = 0; r < 7; ++r)
      u4 = fmaf(encode[n * 7 + r] * sw[r], G2[r * 64 + col], u4);
    float rs = 0.5f * (br + u4);
    float nr = fmaxf(sqrtf(wave_sum64(rs * rs)), 1e-12f);
    float nb = fmaxf(sqrtf(wave_sum64(br * br)), 1e-12f);
    float nu = fmaxf(sqrtf(wave_sum64(u4 * u4)), 1e-12f);
    size_t idx = (size_t)n * 64 + col;
    out[idx] = rs / nr;
    out[(size_t)NDIM * 64 + idx] = br / nb;
    out[2 * (size_t)NDIM * 64 + idx] = u4 / nu;
  }
}

// ---------------------------------------------------------------------------
// Z2t[64][4096] bf16 = (U1 @ W2)^T
// ---------------------------------------------------------------------------
__global__ __launch_bounds__(256) void k_z2t(const float* __restrict__ U1,
    const float* __restrict__ W2, unsigned short* __restrict__ Z2t) {
  __shared__ float W2s[64][65];
  const int n0 = blockIdx.x * 64;
  const int j = threadIdx.x & 63;
  const int g = threadIdx.x >> 6;
  for (int r = g; r < 64; r += 4) W2s[r][j] = W2[r * 64 + j];
  __syncthreads();
  float acc[16];
#pragma unroll
  for (int r = 0; r < 16; ++r) acc[r] = 0.f;
  const float* Urow = U1 + (size_t)(n0 + g * 16) * 64;
  for (int k = 0; k < 64; ++k) {
    float wv = W2s[k][j];
#pragma unroll
    for (int r = 0; r < 16; ++r) acc[r] = fmaf(Urow[r * 64 + k], wv, acc[r]);
  }
  unsigned short ov[16];
#pragma unroll
  for (int r = 0; r < 16; ++r) ov[r] = f2bf(acc[r]);
  *(uint4*)(Z2t + (size_t)j * NDIM + n0 + g * 16)     = *(const uint4*)&ov[0];
  *(uint4*)(Z2t + (size_t)j * NDIM + n0 + g * 16 + 8) = *(const uint4*)&ov[8];
}

// ---------------------------------------------------------------------------
__global__ __launch_bounds__(512) void k_zero_small(float* __restrict__ g,
    unsigned* __restrict__ scnt) {
  int t = threadIdx.x;
  if (t < 448) g[t] = 0.f;
  if (t == 448) *scnt = 0u;
}

// ---------------------------------------------------------------------------
// S = E^T @ (E*sw)  (7x7),  c = colsum(E)  (7) — wave butterfly reduction
// ---------------------------------------------------------------------------
__global__ __launch_bounds__(256) void k_sc(const float* __restrict__ encode,
    const float* __restrict__ sw, float* __restrict__ S, float* __restrict__ c) {
  __shared__ float red[4][56];
  float sl[49], cl[7];
#pragma unroll
  for (int i = 0; i < 49; ++i) sl[i] = 0.f;
#pragma unroll
  for (int i = 0; i < 7; ++i) cl[i] = 0.f;
  for (int n = threadIdx.x; n < NDIM; n += 256) {
    float e[7];
#pragma unroll
    for (int r = 0; r < 7; ++r) e[r] = encode[n * 7 + r];
#pragma unroll
    for (int i = 0; i < 7; ++i) {
      cl[i] += e[i];
#pragma unroll
      for (int j = 0; j < 7; ++j) sl[i * 7 + j] = fmaf(e[i], e[j], sl[i * 7 + j]);
    }
  }
  const int lane = threadIdx.x & 63;
  const int w = threadIdx.x >> 6;
#pragma unroll
  for (int i = 0; i < 49; ++i) {
#pragma unroll
    for (int o = 32; o > 0; o >>= 1) sl[i] += __shfl_xor(sl[i], o, 64);
  }
#pragma unroll
  for (int i = 0; i < 7; ++i) {
#pragma unroll
    for (int o = 32; o > 0; o >>= 1) cl[i] += __shfl_xor(cl[i], o, 64);
  }
  if (lane == 0) {
#pragma unroll
    for (int i = 0; i < 49; ++i) red[w][i] = sl[i];
#pragma unroll
    for (int i = 0; i < 7; ++i) red[w][49 + i] = cl[i];
  }
  __syncthreads();
  if (threadIdx.x < 49)
    S[threadIdx.x] = (red[0][threadIdx.x] + red[1][threadIdx.x] + red[2][threadIdx.x] + red[3][threadIdx.x]) * sw[threadIdx.x % 7];
  if (threadIdx.x >= 49 && threadIdx.x < 56) {
    int i = threadIdx.x;
    c[i - 49] = red[0][i] + red[1][i] + red[2][i] + red[3][i];
  }
}

// ---------------------------------------------------------------------------
// G1 = E^T @ Z1  (7x64)
// ---------------------------------------------------------------------------
__global__ __launch_bounds__(256) void k_g1(const float* __restrict__ encode,
    const float* __restrict__ Z1, float* __restrict__ G1) {
  const int j = threadIdx.x & 63;
  const int grp = threadIdx.x >> 6;
  const int n0 = blockIdx.x * 128 + grp * 32;
  float acc[7];
#pragma unroll
  for (int r = 0; r < 7; ++r) acc[r] = 0.f;
  for (int i = 0; i < 32; ++i) {
    int n = n0 + i;
    float z = Z1[(size_t)n * 64 + j];
#pragma unroll
    for (int r = 0; r < 7; ++r) acc[r] = fmaf(encode[n * 7 + r], z, acc[r]);
  }
#pragma unroll
  for (int r = 0; r < 7; ++r) atomicAdd(&G1[r * 64 + j], acc[r]);
}

// ---------------------------------------------------------------------------
// G2 = S @ (G1 @ W2) + c (x) (b1 @ W2)    (7x64)
// ---------------------------------------------------------------------------
__global__ __launch_bounds__(64) void k_g2(const float* __restrict__ S,
    const float* __restrict__ c, const float* __restrict__ G1,
    const float* __restrict__ W2, const float* __restrict__ b1,
    float* __restrict__ G2) {
  int j = threadIdx.x;
  float h = 0.f;
  for (int k = 0; k < 64; ++k) h = fmaf(b1[k], W2[k * 64 + j], h);
  float gw[7];
#pragma unroll
  for (int r = 0; r < 7; ++r) {
    float v = 0.f;
    for (int k = 0; k < 64; ++k) v = fmaf(G1[r * 64 + k], W2[k * 64 + j], v);
    gw[r] = v;
  }
#pragma unroll
  for (int r = 0; r < 7; ++r) {
    float v = c[r] * h;
#pragma unroll
    for (int q = 0; q < 7; ++q) v = fmaf(S[r * 7 + q], gw[q], v);
    G2[r * 64 + j] = v;
  }
}

// ---------------------------------------------------------------------------
extern "C" void kernel_launch(void* const* d_in, const int* in_sizes, int n_in,
                              void* d_out, int out_size, void* d_ws, size_t ws_size,
                              hipStream_t stream) {
  const float* feature  = (const float*)d_in[0];
  const float* A        = (const float*)d_in[1];
  const float* encode   = (const float*)d_in[2];
  const float* W1       = (const float*)d_in[3];
  const float* b1       = (const float*)d_in[4];
  const float* W2       = (const float*)d_in[5];
  const float* b2       = (const float*)d_in[6];
  const float* wb       = (const float*)d_in[7];
  const float* Mri      = (const float*)d_in[8];
  const float* strength = (const float*)d_in[9];
  const float* sw       = (const float*)d_in[10];
  float* out = (float*)d_out;

  const size_t NV = (size_t)NDIM * 64;
  unsigned* sidx = (unsigned*)d_ws;                       // SCAP u32
  float* sval = (float*)(sidx + SCAP);                    // SCAP f32
  unsigned* scnt = (unsigned*)(sval + SCAP);              // 1 u32
  unsigned short* Mm = (unsigned short*)d_ws + NNSZ;      // NNSZ bf16
  unsigned short* Fb = Mm + NNSZ;                         // NNSZ bf16
  float* Z1 = (float*)(Fb + NNSZ);                        // NV f32
  float* U1 = Z1 + NV;
  float* U2 = U1 + NV;                                    // (slot kept, unused)
  unsigned short* Z1t = (unsigned short*)(U2 + NV);       // NV bf16
  unsigned short* Z2t = Z1t + NV;                         // NV bf16
  float* G1 = (float*)(Z2t + NV);                         // 448
  float* S  = G1 + 448;
  float* c  = S + 49;
  float* G2 = c + 7;

  hipLaunchKernelGGL(k_zero_small, dim3(1), dim3(512), 0, stream, G1, scnt);
  hipLaunchKernelGGL(k_pass1, dim3(16384), dim3(256), 0, stream, A, wb, Mri, strength, Mm, sidx, sval, scnt);
  hipLaunchKernelGGL(k_pass2, dim3(64, 64), dim3(256), 0, stream, Mm, Fb);
  hipLaunchKernelGGL(k_fix, dim3(32), dim3(256), 0, stream, sidx, sval, scnt, Fb);
  hipLaunchKernelGGL(k_z1, dim3(NDIM), dim3(64), 0, stream, feature, W1, Z1);
  hipLaunchKernelGGL(k_transpose_bf16, dim3(64), dim3(256), 0, stream, Z1, Z1t);
  hipLaunchKernelGGL(k_sc, dim3(1), dim3(256), 0, stream, encode, sw, S, c);
  hipLaunchKernelGGL(k_g1, dim3(32), dim3(256), 0, stream, encode, Z1, G1);
  hipLaunchKernelGGL(k_g2, dim3(1), dim3(64), 0, stream, S, c, G1, W2, b1, G2);
  hipLaunchKernelGGL(k_mfma_gemm, dim3(NDIM / 16), dim3(512), 0, stream, Fb, Z1t, b1, U1);
  hipLaunchKernelGGL(k_z2t, dim3(64), dim3(256), 0, stream, U1, W2, Z2t);
  hipLaunchKernelGGL(k_gemm2f, dim3(NDIM / 16), dim3(512), 0, stream, Fb, Z2t, b2, U1, encode, sw, G2, out);
}